// Round 2
// baseline (554.493 us; speedup 1.0000x reference)
//
#include <hip/hip_runtime.h>
#include <math.h>

#define HDIM 7168
#define NEXP 256
#define NTOK 8192
#define BM 64
#define KS 8
#define KCH (HDIM / KS)      // 896 source-k per block
#define NR (KCH / 32)        // 28 rounds of 32 source-k
#define PITCH 72             // f16 slots per LDS row: 32 hi | 32 lo | 8 pad

typedef _Float16 f16x8 __attribute__((ext_vector_type(8)));
typedef _Float16 f16x4 __attribute__((ext_vector_type(4)));
typedef float f32x4 __attribute__((ext_vector_type(4)));

__device__ __forceinline__ f16x8 hi8(float4 u, float4 v) {
    f16x8 h;
    h[0] = (_Float16)u.x; h[1] = (_Float16)u.y; h[2] = (_Float16)u.z; h[3] = (_Float16)u.w;
    h[4] = (_Float16)v.x; h[5] = (_Float16)v.y; h[6] = (_Float16)v.z; h[7] = (_Float16)v.w;
    return h;
}
__device__ __forceinline__ f16x8 lo8(float4 u, float4 v, f16x8 h) {
    f16x8 l;
    l[0] = (_Float16)(u.x - (float)h[0]); l[1] = (_Float16)(u.y - (float)h[1]);
    l[2] = (_Float16)(u.z - (float)h[2]); l[3] = (_Float16)(u.w - (float)h[3]);
    l[4] = (_Float16)(v.x - (float)h[4]); l[5] = (_Float16)(v.y - (float)h[5]);
    l[6] = (_Float16)(v.z - (float)h[6]); l[7] = (_Float16)(v.w - (float)h[7]);
    return l;
}
__device__ __forceinline__ f16x4 hi4(float4 u) {
    f16x4 h;
    h[0] = (_Float16)u.x; h[1] = (_Float16)u.y; h[2] = (_Float16)u.z; h[3] = (_Float16)u.w;
    return h;
}
__device__ __forceinline__ f16x4 lo4(float4 u, f16x4 h) {
    f16x4 l;
    l[0] = (_Float16)(u.x - (float)h[0]); l[1] = (_Float16)(u.y - (float)h[1]);
    l[2] = (_Float16)(u.z - (float)h[2]); l[3] = (_Float16)(u.w - (float)h[3]);
    return l;
}

// ---------------------------------------------------------------------------
// Router GEMM via f16 MFMA 2-term split: logits = hs @ W^T.
// a = ah + al (f16 each); C = Ah*Bh + Ah*Bl + Al*Bh  (al*bl ~ 2^-20, dropped).
// W scaled x256 in-reg so W_lo is f16-normal; epilogue multiplies by 1/256.
// Verified layouts (learn_hip m89/m91/m120): A/B frag [idx=lane&15][k=quad*8+j],
// C/D col=lane&15, row=quad*4+reg.
//
// v3 structure (fixing v2's exposed-latency stall: VGPR=92 proved the
// software pipeline was deallocated; 2 waves/SIMD gave no TLP cover):
//   Wave tile 32x64 -> acc = 32 VGPRs, full prefetch pipeline fits <128.
//   Block 64x256, 512 thr, 8 waves as 2m x 4n. KS=8 -> grid (8,128) = 1024
//   blocks = 2 blocks/CU = 16 waves/CU = 4 waves/SIMD (__launch_bounds__ 512,4).
//   Two independently-barriered blocks per CU + 4-deep TLP hide L2 latency.
//   blockIdx.x = k-slice = XCD id -> each XCD's 918 KB W-slice is L2-resident.
//   A: global->reg->f16 hi/lo->LDS, double-buffered, one barrier per round.
//   B: per-lane fp32 fragment gathers from L2, converted in-reg (no LDS).
// ---------------------------------------------------------------------------
__global__ __launch_bounds__(512, 4)
void router_gemm_mfma(const float* __restrict__ hs,
                      const float* __restrict__ W,
                      float* __restrict__ logits)
{
    __shared__ __align__(16) _Float16 Alds[2][BM * PITCH];   // 2 x 9216 B

    const int tid  = threadIdx.x;
    const int lane = tid & 63;
    const int wave = tid >> 6;           // 0..7
    const int kb = blockIdx.x * KCH;     // k-split offset (== XCD id)
    const int bm = blockIdx.y * BM;

    const int wm = (wave >> 2) << 5;     // wave row band: 0 / 32
    const int wc = (wave & 3) << 6;      // wave col band: 0/64/128/192
    const int fm = lane & 15;
    const int quad = lane >> 4;

    // A staging: thread -> row tid>>3 (0..63), k-quarter (tid&7)*4
    const int arow = tid >> 3;
    const int ak   = (tid & 7) << 2;
    const float* Ap = hs + (size_t)(bm + arow) * HDIM + kb + ak;
    // B frag source: lane covers W row (wc + i*16 + fm), k = quad*8..+7
    const float* Bp = W + (size_t)(wc + fm) * HDIM + kb + quad * 8;

    f32x4 acc[2][4];
#pragma unroll
    for (int i = 0; i < 2; i++)
#pragma unroll
        for (int j = 0; j < 4; j++) acc[i][j] = (f32x4)0.0f;

    // ---- prologue: load round 0 (A 4 floats, B 4 tiles x 8 floats) ----
    float4 a0 = *(const float4*)Ap;
    float4 bu[4], bv[4];
#pragma unroll
    for (int i = 0; i < 4; i++) {
        const float* q = Bp + (size_t)i * (16 * HDIM);
        bu[i] = *(const float4*)(q + 0);
        bv[i] = *(const float4*)(q + 4);
    }
    {   // stage A round 0 into buffer 0
        f16x4 h = hi4(a0);
        f16x4 l = lo4(a0, h);
        *(f16x4*)&Alds[0][arow * PITCH + ak]      = h;
        *(f16x4*)&Alds[0][arow * PITCH + 32 + ak] = l;
    }
    __syncthreads();

#pragma unroll 2
    for (int r = 0; r < NR; ++r) {
        const int cur = r & 1;
        // ---- B: convert prefetched fp32 (x256) to hi/lo f16 frags ----
        f16x8 bh[4], bl[4];
#pragma unroll
        for (int i = 0; i < 4; i++) {
            float4 s0 = make_float4(bu[i].x * 256.0f, bu[i].y * 256.0f,
                                    bu[i].z * 256.0f, bu[i].w * 256.0f);
            float4 s1 = make_float4(bv[i].x * 256.0f, bv[i].y * 256.0f,
                                    bv[i].z * 256.0f, bv[i].w * 256.0f);
            bh[i] = hi8(s0, s1);
            bl[i] = lo8(s0, s1, bh[i]);
        }
        // ---- prefetch next round (latency hidden under MFMA phase) ----
        if (r + 1 < NR) {
            a0 = *(const float4*)(Ap + (r + 1) * 32);
            const float* Bn = Bp + (r + 1) * 32;
#pragma unroll
            for (int i = 0; i < 4; i++) {
                const float* q = Bn + (size_t)i * (16 * HDIM);
                bu[i] = *(const float4*)(q + 0);
                bv[i] = *(const float4*)(q + 4);
            }
        }
        // ---- A frags from LDS ----
        f16x8 af[2], alo[2];
#pragma unroll
        for (int im = 0; im < 2; im++) {
            const int off = (wm + im * 16 + fm) * PITCH + quad * 8;
            af[im]  = *(const f16x8*)&Alds[cur][off];
            alo[im] = *(const f16x8*)&Alds[cur][off + 32];
        }
        // ---- MFMA: 24 per wave over this 32-k chunk ----
        // P1: Ah * Bh
#pragma unroll
        for (int im = 0; im < 2; im++)
#pragma unroll
            for (int in_ = 0; in_ < 4; in_++)
                acc[im][in_] = __builtin_amdgcn_mfma_f32_16x16x32_f16(af[im], bh[in_], acc[im][in_], 0, 0, 0);
        // P2: Ah * Bl
#pragma unroll
        for (int im = 0; im < 2; im++)
#pragma unroll
            for (int in_ = 0; in_ < 4; in_++)
                acc[im][in_] = __builtin_amdgcn_mfma_f32_16x16x32_f16(af[im], bl[in_], acc[im][in_], 0, 0, 0);
        // P3: Al * Bh
#pragma unroll
        for (int im = 0; im < 2; im++)
#pragma unroll
            for (int in_ = 0; in_ < 4; in_++)
                acc[im][in_] = __builtin_amdgcn_mfma_f32_16x16x32_f16(alo[im], bh[in_], acc[im][in_], 0, 0, 0);
        // ---- stage next-round A into the other buffer ----
        if (r + 1 < NR) {
            f16x4 h = hi4(a0);
            f16x4 l = lo4(a0, h);
            *(f16x4*)&Alds[cur ^ 1][arow * PITCH + ak]      = h;
            *(f16x4*)&Alds[cur ^ 1][arow * PITCH + 32 + ak] = l;
        }
        __syncthreads();
    }

    // ---- epilogue: undo x256 on B, combine K-splits via atomics ----
#pragma unroll
    for (int im = 0; im < 2; im++) {
#pragma unroll
        for (int in_ = 0; in_ < 4; in_++) {
            const int n = wc + in_ * 16 + fm;
#pragma unroll
            for (int rr = 0; rr < 4; rr++) {
                const int m = bm + wm + im * 16 + quad * 4 + rr;
                unsafeAtomicAdd(&logits[(size_t)m * NEXP + n], acc[im][in_][rr] * 0.00390625f);
            }
        }
    }
}

// ---------------------------------------------------------------------------
// Kernel 2: one wave per token. lane l holds experts 4l..4l+3.
// Replicates jax.lax.top_k semantics exactly: descending, ties -> lower index;
// unselected groups contribute literal 0.0f candidates.
// (Deliberately unchanged this round: if the ~240us total-vs-GEMM gap is this
//  kernel, it will surface in top-5 once the GEMM drops below it.)
// ---------------------------------------------------------------------------
__global__ __launch_bounds__(256)
void router_topk_kernel(const float* __restrict__ logits,
                        const float* __restrict__ bias,
                        const float* __restrict__ corr,
                        float* __restrict__ out)
{
    const int lane = threadIdx.x & 63;
    const int wave = threadIdx.x >> 6;
    const int t = blockIdx.x * 4 + wave;
    const float* row = logits + (size_t)t * NEXP;
    const int e0 = lane << 2;

    float4 lg = *(const float4*)(row + e0);
    float4 bb = *(const float4*)(bias + e0);
    float4 cc = *(const float4*)(corr + e0);

    float xs[4] = {lg.x + bb.x, lg.y + bb.y, lg.z + bb.z, lg.w + bb.w};
    float cs[4] = {cc.x, cc.y, cc.z, cc.w};
    float s[4], sc[4], mv[4];
#pragma unroll
    for (int i = 0; i < 4; i++) {
        s[i] = 1.0f / (1.0f + expf(-xs[i]));
        sc[i] = s[i] + cs[i];
    }

    // ---- per-group (32 experts = 8 lanes) top-2 sum ----
    float m1 = fmaxf(sc[0], sc[1]);
    float m2 = fminf(sc[0], sc[1]);
    if (sc[2] > m1) { m2 = m1; m1 = sc[2]; } else { m2 = fmaxf(m2, sc[2]); }
    if (sc[3] > m1) { m2 = m1; m1 = sc[3]; } else { m2 = fmaxf(m2, sc[3]); }
#pragma unroll
    for (int off = 1; off <= 4; off <<= 1) {
        float o1 = __shfl_xor(m1, off);
        float o2 = __shfl_xor(m2, off);
        float hi = fmaxf(m1, o1);
        float lo = fminf(m1, o1);
        m1 = hi;
        m2 = fmaxf(lo, fmaxf(m2, o2));
    }
    const float gscore = m1 + m2;

    // ---- broadcast all 8 group scores, compute top-4 group mask ----
    float gs[8];
#pragma unroll
    for (int j = 0; j < 8; j++) gs[j] = __shfl(gscore, j << 3);
    const int g = lane >> 3;
    int rank = 0;
#pragma unroll
    for (int j = 0; j < 8; j++)
        rank += ((gs[j] > gs[g]) || ((gs[j] == gs[g]) && (j < g))) ? 1 : 0;
    const bool sel = (rank < 4);

#pragma unroll
    for (int i = 0; i < 4; i++) mv[i] = sel ? sc[i] : 0.0f;

    // ---- iterative top-8 wave argmax (stable: ties -> lower index) ----
    int oidx[8];
    float ow[8];
    float wsum = 0.0f;
#pragma unroll
    for (int r = 0; r < 8; r++) {
        float bv = mv[0]; int bi = e0;
        if (mv[1] > bv) { bv = mv[1]; bi = e0 + 1; }
        if (mv[2] > bv) { bv = mv[2]; bi = e0 + 2; }
        if (mv[3] > bv) { bv = mv[3]; bi = e0 + 3; }
#pragma unroll
        for (int off = 32; off >= 1; off >>= 1) {
            float ov = __shfl_xor(bv, off);
            int oi = __shfl_xor(bi, off);
            if ((ov > bv) || ((ov == bv) && (oi < bi))) { bv = ov; bi = oi; }
        }
        // all lanes now agree on (bv, bi)
        const int wl = bi >> 2;
        const int slot = bi & 3;
        float sraw = (slot == 0) ? s[0] : (slot == 1) ? s[1] : (slot == 2) ? s[2] : s[3];
        sraw = __shfl(sraw, wl);
        if (lane == wl) {
            if (slot == 0) mv[0] = -1e30f;
            else if (slot == 1) mv[1] = -1e30f;
            else if (slot == 2) mv[2] = -1e30f;
            else mv[3] = -1e30f;
        }
        oidx[r] = bi;
        ow[r] = sraw;
        wsum += sraw;
    }

    if (lane == 0) {
        const float d = wsum + 1e-20f;
        float* oi_p = out + (size_t)t * 8;
        float* ow_p = out + (size_t)NTOK * 8 + (size_t)t * 8;
#pragma unroll
        for (int r = 0; r < 8; r++) {
            oi_p[r] = (float)oidx[r];
            ow_p[r] = (ow[r] / d) * 2.5f;
        }
    }
}

extern "C" void kernel_launch(void* const* d_in, const int* in_sizes, int n_in,
                              void* d_out, int out_size, void* d_ws, size_t ws_size,
                              hipStream_t stream)
{
    const float* hs   = (const float*)d_in[0];   // [8192, 7168]
    const float* W    = (const float*)d_in[1];   // [256, 7168]
    const float* b    = (const float*)d_in[2];   // [256]
    const float* corr = (const float*)d_in[3];   // [256]
    float* out = (float*)d_out;                  // 65536 idx-as-float + 65536 weights
    float* logits = (float*)d_ws;                // 8192*256 fp32 = 8 MB scratch

    // zero the logits accumulator (split-K atomics land here)
    hipMemsetAsync(logits, 0, (size_t)NTOK * NEXP * sizeof(float), stream);

    dim3 g1(KS, NTOK / BM);                      // (8, 128) -> 1024 blocks, 2/CU
    router_gemm_mfma<<<g1, 512, 0, stream>>>(hs, W, logits);
    router_topk_kernel<<<NTOK / 4, 256, 0, stream>>>(logits, b, corr, out);
}

// Round 3
// 427.588 us; speedup vs baseline: 1.2968x; 1.2968x over previous
//
#include <hip/hip_runtime.h>
#include <math.h>

#define HDIM 7168
#define NEXP 256
#define NTOK 8192

// ---- v4 fast-path geometry (barrier-free, LDS-free) ----
#define KS 8                  // k-splits (== XCD count)
#define KSTEPS 224            // HDIM/32 global k-steps
#define KSPW 28               // k-steps per wave (KSTEPS/KS)
#define NTILES 16             // NEXP/16 n-tiles
#define WT_M 64               // wave tile m (4 x 16)
#define WT_N 128              // wave tile n (8 x 16)

#define LOGITS_F32 (NTOK * NEXP)                  // 2,097,152 floats = 8 MB
#define W16_PLANE_F16 (NTILES * KSTEPS * 512)     // 1,835,008 f16 = 3.5 MB
#define WS_NEEDED (LOGITS_F32 * 4 + 2 * W16_PLANE_F16 * 2)   // 15,728,640 B

typedef _Float16 f16x8 __attribute__((ext_vector_type(8)));
typedef float f32x4 __attribute__((ext_vector_type(4)));

__device__ __forceinline__ f16x8 hi8(float4 u, float4 v) {
    f16x8 h;
    h[0] = (_Float16)u.x; h[1] = (_Float16)u.y; h[2] = (_Float16)u.z; h[3] = (_Float16)u.w;
    h[4] = (_Float16)v.x; h[5] = (_Float16)v.y; h[6] = (_Float16)v.z; h[7] = (_Float16)v.w;
    return h;
}
__device__ __forceinline__ f16x8 lo8(float4 u, float4 v, f16x8 h) {
    f16x8 l;
    l[0] = (_Float16)(u.x - (float)h[0]); l[1] = (_Float16)(u.y - (float)h[1]);
    l[2] = (_Float16)(u.z - (float)h[2]); l[3] = (_Float16)(u.w - (float)h[3]);
    l[4] = (_Float16)(v.x - (float)h[4]); l[5] = (_Float16)(v.y - (float)h[5]);
    l[6] = (_Float16)(v.z - (float)h[6]); l[7] = (_Float16)(v.w - (float)h[7]);
    return l;
}

// ---------------------------------------------------------------------------
// Kernel 0: convert W (256x7168 fp32) -> f16 hi/lo planes in MFMA-FRAGMENT
// order. Frag f = nt*KSTEPS + ksi holds the B-fragment of n-tile nt at k-step
// ksi: element [lane][j] = W[nt*16 + (lane&15)][ksi*32 + (lane>>4)*8 + j]*256.
// Same scale-x256 hi/lo math as the previous in-loop conversion (bit-identical).
// One-time cost ~5 us; lets the GEMM read B as coalesced 16B/lane streams.
// ---------------------------------------------------------------------------
__global__ __launch_bounds__(256)
void conv_w_kernel(const float* __restrict__ W,
                   _Float16* __restrict__ whi,
                   _Float16* __restrict__ wlo)
{
    const int t = blockIdx.x * 256 + threadIdx.x;   // 0 .. 229375
    const int lane = t & 63;
    const int f = t >> 6;                           // 0 .. 3583
    const int ksi = f % KSTEPS;
    const int nt  = f / KSTEPS;
    const int n = nt * 16 + (lane & 15);
    const int k = ksi * 32 + (lane >> 4) * 8;
    const float* src = W + (size_t)n * HDIM + k;
    float4 u = *(const float4*)(src + 0);
    float4 v = *(const float4*)(src + 4);
    u.x *= 256.0f; u.y *= 256.0f; u.z *= 256.0f; u.w *= 256.0f;
    v.x *= 256.0f; v.y *= 256.0f; v.z *= 256.0f; v.w *= 256.0f;
    f16x8 h = hi8(u, v);
    f16x8 l = lo8(u, v, h);
    *(f16x8*)&whi[(size_t)f * 512 + lane * 8] = h;
    *(f16x8*)&wlo[(size_t)f * 512 + lane * 8] = l;
}

// ---------------------------------------------------------------------------
// Kernel 1 (v4): barrier-free LDS-free router GEMM.
// logits = hs @ W^T via 3-product f16 split (Ah*Bh + Ah*Bl + Al*Bh).
// Wave tile 64m x 128n x full 896k chunk; acc[4][8] = 128 VGPR.
// Waves fully independent: no __syncthreads -> no vmcnt(0) barrier drain;
// compiler free to pipeline with counted vmcnt. B frags are coalesced
// lane*16B loads from the precomputed planes (zero VALU, zero LDS).
// A loaded per-lane (16 rows x 128B per instr pair, full-line usage),
// converted hi/lo in-reg once (x2 redundancy across the 2 n-halves).
// Grid: bx = ks + 8*(nh + 2*mig) -> ks == bx%8 == XCD id, so each XCD's L2
// holds only its 896 KB W16 k-slice. 512 blocks x 4 waves = 2 blocks/CU.
// Block's 4 waves share the same B stream (L1 hits) and read 256 contiguous
// A rows. Split-K combined via atomics (epilogue undoes the x256).
// ---------------------------------------------------------------------------
__global__ __launch_bounds__(256, 2)
void router_gemm_v4(const float* __restrict__ hs,
                    const _Float16* __restrict__ whi,
                    const _Float16* __restrict__ wlo,
                    float* __restrict__ logits)
{
    const int tid  = threadIdx.x;
    const int lane = tid & 63;
    const int wv   = tid >> 6;            // 0..3
    const int bx   = blockIdx.x;
    const int ks   = bx & 7;
    const int nh   = (bx >> 3) & 1;
    const int mig  = bx >> 4;             // 0..31
    const int mi   = mig * 4 + wv;        // 0..127
    const int m0   = mi * WT_M;
    const int fm   = lane & 15;
    const int quad = lane >> 4;
    const int ks0  = ks * KSPW;           // first global k-step

    const float* Ap = hs + (size_t)(m0 + fm) * HDIM + ks0 * 32 + quad * 8;
    const _Float16* bhp = whi + ((size_t)(nh * 8) * KSTEPS + ks0) * 512 + lane * 8;
    const _Float16* blp = wlo + ((size_t)(nh * 8) * KSTEPS + ks0) * 512 + lane * 8;

    f32x4 acc[4][8];
#pragma unroll
    for (int i = 0; i < 4; i++)
#pragma unroll
        for (int j = 0; j < 8; j++) acc[i][j] = (f32x4)0.0f;

    // preload B half 0 of round 0
    f16x8 b0h[4], b0l[4], b1h[4], b1l[4];
#pragma unroll
    for (int i = 0; i < 4; i++) {
        b0h[i] = *(const f16x8*)(bhp + (size_t)i * (KSTEPS * 512));
        b0l[i] = *(const f16x8*)(blp + (size_t)i * (KSTEPS * 512));
    }

#pragma unroll 1
    for (int r = 0; r < KSPW; ++r) {
        // ---- A: load 8 fp32/row for 4 rows, convert hi/lo in-reg ----
        f16x8 af[4], al_[4];
#pragma unroll
        for (int im = 0; im < 4; im++) {
            const float* p = Ap + (size_t)im * (16 * HDIM) + r * 32;
            float4 u = *(const float4*)(p + 0);
            float4 v = *(const float4*)(p + 4);
            af[im]  = hi8(u, v);
            al_[im] = lo8(u, v, af[im]);
        }
        // ---- issue B half 1 of this round (hidden under half-0 MFMAs) ----
#pragma unroll
        for (int i = 0; i < 4; i++) {
            b1h[i] = *(const f16x8*)(bhp + ((size_t)(4 + i) * KSTEPS + r) * 512);
            b1l[i] = *(const f16x8*)(blp + ((size_t)(4 + i) * KSTEPS + r) * 512);
        }
        // ---- MFMA half 0: 48 ----
#pragma unroll
        for (int i = 0; i < 4; i++) {
#pragma unroll
            for (int im = 0; im < 4; im++)
                acc[im][i] = __builtin_amdgcn_mfma_f32_16x16x32_f16(af[im], b0h[i], acc[im][i], 0, 0, 0);
#pragma unroll
            for (int im = 0; im < 4; im++)
                acc[im][i] = __builtin_amdgcn_mfma_f32_16x16x32_f16(af[im], b0l[i], acc[im][i], 0, 0, 0);
#pragma unroll
            for (int im = 0; im < 4; im++)
                acc[im][i] = __builtin_amdgcn_mfma_f32_16x16x32_f16(al_[im], b0h[i], acc[im][i], 0, 0, 0);
        }
        // ---- issue B half 0 of next round (hidden under half-1 MFMAs) ----
        if (r + 1 < KSPW) {
#pragma unroll
            for (int i = 0; i < 4; i++) {
                b0h[i] = *(const f16x8*)(bhp + ((size_t)i * KSTEPS + (r + 1)) * 512);
                b0l[i] = *(const f16x8*)(blp + ((size_t)i * KSTEPS + (r + 1)) * 512);
            }
        }
        // ---- MFMA half 1: 48 ----
#pragma unroll
        for (int i = 0; i < 4; i++) {
#pragma unroll
            for (int im = 0; im < 4; im++)
                acc[im][4 + i] = __builtin_amdgcn_mfma_f32_16x16x32_f16(af[im], b1h[i], acc[im][4 + i], 0, 0, 0);
#pragma unroll
            for (int im = 0; im < 4; im++)
                acc[im][4 + i] = __builtin_amdgcn_mfma_f32_16x16x32_f16(af[im], b1l[i], acc[im][4 + i], 0, 0, 0);
#pragma unroll
            for (int im = 0; im < 4; im++)
                acc[im][4 + i] = __builtin_amdgcn_mfma_f32_16x16x32_f16(al_[im], b1h[i], acc[im][4 + i], 0, 0, 0);
        }
    }

    // ---- epilogue: undo x256 on B, combine K-splits via atomics ----
#pragma unroll
    for (int im = 0; im < 4; im++) {
#pragma unroll
        for (int i = 0; i < 8; i++) {
            const int n = nh * WT_N + i * 16 + fm;
#pragma unroll
            for (int rr = 0; rr < 4; rr++) {
                const int m = m0 + im * 16 + quad * 4 + rr;
                unsafeAtomicAdd(&logits[(size_t)m * NEXP + n], acc[im][i][rr] * 0.00390625f);
            }
        }
    }
}

// ---------------------------------------------------------------------------
// Fallback GEMM (v2, proven absmax=0, 188us) used when ws_size < WS_NEEDED.
// ---------------------------------------------------------------------------
#define FB_BM 128
#define FB_KS 4
#define FB_KCH (HDIM / FB_KS)
#define FB_NR (FB_KCH / 32)
#define FB_PITCH 72

__global__ __launch_bounds__(512, 2)
void router_gemm_fb(const float* __restrict__ hs,
                    const float* __restrict__ W,
                    float* __restrict__ logits)
{
    __shared__ __align__(16) _Float16 Alds[2][FB_BM * FB_PITCH];

    const int tid  = threadIdx.x;
    const int lane = tid & 63;
    const int wave = tid >> 6;
    const int kb = blockIdx.x * FB_KCH;
    const int bm = blockIdx.y * FB_BM;

    const int wm = (wave >> 2) << 6;
    const int wc = wave & 3;
    const int fm = lane & 15;
    const int quad = lane >> 4;

    const int arow = tid >> 2;
    const int akh  = (tid & 3) << 3;
    const float* Ap = hs + (size_t)(bm + arow) * HDIM + kb + akh;
    const float* Bp = W + (size_t)(wc * 64 + fm) * HDIM + kb + quad * 8;

    f32x4 acc[4][4];
#pragma unroll
    for (int i = 0; i < 4; i++)
#pragma unroll
        for (int j = 0; j < 4; j++) acc[i][j] = (f32x4)0.0f;

    float4 a0 = *(const float4*)(Ap + 0);
    float4 a1 = *(const float4*)(Ap + 4);
    float4 bu[4], bv[4];
#pragma unroll
    for (int i = 0; i < 4; i++) {
        const float* q = Bp + (size_t)i * (16 * HDIM);
        bu[i] = *(const float4*)(q + 0);
        bv[i] = *(const float4*)(q + 4);
    }
    {
        f16x8 h = hi8(a0, a1);
        f16x8 l = lo8(a0, a1, h);
        *(f16x8*)&Alds[0][arow * FB_PITCH + akh]      = h;
        *(f16x8*)&Alds[0][arow * FB_PITCH + 32 + akh] = l;
    }
    __syncthreads();

#pragma unroll 2
    for (int r = 0; r < FB_NR; ++r) {
        const int cur = r & 1;
        f16x8 bh[4], bl[4];
#pragma unroll
        for (int i = 0; i < 4; i++) {
            float4 s0 = make_float4(bu[i].x * 256.0f, bu[i].y * 256.0f,
                                    bu[i].z * 256.0f, bu[i].w * 256.0f);
            float4 s1 = make_float4(bv[i].x * 256.0f, bv[i].y * 256.0f,
                                    bv[i].z * 256.0f, bv[i].w * 256.0f);
            bh[i] = hi8(s0, s1);
            bl[i] = lo8(s0, s1, bh[i]);
        }
        if (r + 1 < FB_NR) {
            const float* An = Ap + (r + 1) * 32;
            a0 = *(const float4*)(An + 0);
            a1 = *(const float4*)(An + 4);
            const float* Bn = Bp + (r + 1) * 32;
#pragma unroll
            for (int i = 0; i < 4; i++) {
                const float* q = Bn + (size_t)i * (16 * HDIM);
                bu[i] = *(const float4*)(q + 0);
                bv[i] = *(const float4*)(q + 4);
            }
        }
        f16x8 af[4], alo[4];
#pragma unroll
        for (int im = 0; im < 4; im++) {
            const int off = (wm + im * 16 + fm) * FB_PITCH + quad * 8;
            af[im]  = *(const f16x8*)&Alds[cur][off];
            alo[im] = *(const f16x8*)&Alds[cur][off + 32];
        }
#pragma unroll
        for (int im = 0; im < 4; im++)
#pragma unroll
            for (int in_ = 0; in_ < 4; in_++)
                acc[im][in_] = __builtin_amdgcn_mfma_f32_16x16x32_f16(af[im], bh[in_], acc[im][in_], 0, 0, 0);
#pragma unroll
        for (int im = 0; im < 4; im++)
#pragma unroll
            for (int in_ = 0; in_ < 4; in_++)
                acc[im][in_] = __builtin_amdgcn_mfma_f32_16x16x32_f16(af[im], bl[in_], acc[im][in_], 0, 0, 0);
#pragma unroll
        for (int im = 0; im < 4; im++)
#pragma unroll
            for (int in_ = 0; in_ < 4; in_++)
                acc[im][in_] = __builtin_amdgcn_mfma_f32_16x16x32_f16(alo[im], bh[in_], acc[im][in_], 0, 0, 0);
        if (r + 1 < FB_NR) {
            f16x8 h = hi8(a0, a1);
            f16x8 l = lo8(a0, a1, h);
            *(f16x8*)&Alds[cur ^ 1][arow * FB_PITCH + akh]      = h;
            *(f16x8*)&Alds[cur ^ 1][arow * FB_PITCH + 32 + akh] = l;
        }
        __syncthreads();
    }

#pragma unroll
    for (int im = 0; im < 4; im++) {
#pragma unroll
        for (int in_ = 0; in_ < 4; in_++) {
            const int n = wc * 64 + in_ * 16 + fm;
#pragma unroll
            for (int rr = 0; rr < 4; rr++) {
                const int m = bm + wm + im * 16 + quad * 4 + rr;
                unsafeAtomicAdd(&logits[(size_t)m * NEXP + n], acc[im][in_][rr] * 0.00390625f);
            }
        }
    }
}

// ---------------------------------------------------------------------------
// Kernel 2: one wave per token. lane l holds experts 4l..4l+3.
// Replicates jax.lax.top_k semantics exactly: descending, ties -> lower index;
// unselected groups contribute literal 0.0f candidates. (Unchanged.)
// ---------------------------------------------------------------------------
__global__ __launch_bounds__(256)
void router_topk_kernel(const float* __restrict__ logits,
                        const float* __restrict__ bias,
                        const float* __restrict__ corr,
                        float* __restrict__ out)
{
    const int lane = threadIdx.x & 63;
    const int wave = threadIdx.x >> 6;
    const int t = blockIdx.x * 4 + wave;
    const float* row = logits + (size_t)t * NEXP;
    const int e0 = lane << 2;

    float4 lg = *(const float4*)(row + e0);
    float4 bb = *(const float4*)(bias + e0);
    float4 cc = *(const float4*)(corr + e0);

    float xs[4] = {lg.x + bb.x, lg.y + bb.y, lg.z + bb.z, lg.w + bb.w};
    float cs[4] = {cc.x, cc.y, cc.z, cc.w};
    float s[4], sc[4], mv[4];
#pragma unroll
    for (int i = 0; i < 4; i++) {
        s[i] = 1.0f / (1.0f + expf(-xs[i]));
        sc[i] = s[i] + cs[i];
    }

    float m1 = fmaxf(sc[0], sc[1]);
    float m2 = fminf(sc[0], sc[1]);
    if (sc[2] > m1) { m2 = m1; m1 = sc[2]; } else { m2 = fmaxf(m2, sc[2]); }
    if (sc[3] > m1) { m2 = m1; m1 = sc[3]; } else { m2 = fmaxf(m2, sc[3]); }
#pragma unroll
    for (int off = 1; off <= 4; off <<= 1) {
        float o1 = __shfl_xor(m1, off);
        float o2 = __shfl_xor(m2, off);
        float hi = fmaxf(m1, o1);
        float lo = fminf(m1, o1);
        m1 = hi;
        m2 = fmaxf(lo, fmaxf(m2, o2));
    }
    const float gscore = m1 + m2;

    float gs[8];
#pragma unroll
    for (int j = 0; j < 8; j++) gs[j] = __shfl(gscore, j << 3);
    const int g = lane >> 3;
    int rank = 0;
#pragma unroll
    for (int j = 0; j < 8; j++)
        rank += ((gs[j] > gs[g]) || ((gs[j] == gs[g]) && (j < g))) ? 1 : 0;
    const bool sel = (rank < 4);

#pragma unroll
    for (int i = 0; i < 4; i++) mv[i] = sel ? sc[i] : 0.0f;

    int oidx[8];
    float ow[8];
    float wsum = 0.0f;
#pragma unroll
    for (int r = 0; r < 8; r++) {
        float bv = mv[0]; int bi = e0;
        if (mv[1] > bv) { bv = mv[1]; bi = e0 + 1; }
        if (mv[2] > bv) { bv = mv[2]; bi = e0 + 2; }
        if (mv[3] > bv) { bv = mv[3]; bi = e0 + 3; }
#pragma unroll
        for (int off = 32; off >= 1; off >>= 1) {
            float ov = __shfl_xor(bv, off);
            int oi = __shfl_xor(bi, off);
            if ((ov > bv) || ((ov == bv) && (oi < bi))) { bv = ov; bi = oi; }
        }
        const int wl = bi >> 2;
        const int slot = bi & 3;
        float sraw = (slot == 0) ? s[0] : (slot == 1) ? s[1] : (slot == 2) ? s[2] : s[3];
        sraw = __shfl(sraw, wl);
        if (lane == wl) {
            if (slot == 0) mv[0] = -1e30f;
            else if (slot == 1) mv[1] = -1e30f;
            else if (slot == 2) mv[2] = -1e30f;
            else mv[3] = -1e30f;
        }
        oidx[r] = bi;
        ow[r] = sraw;
        wsum += sraw;
    }

    if (lane == 0) {
        const float d = wsum + 1e-20f;
        float* oi_p = out + (size_t)t * 8;
        float* ow_p = out + (size_t)NTOK * 8 + (size_t)t * 8;
#pragma unroll
        for (int r = 0; r < 8; r++) {
            oi_p[r] = (float)oidx[r];
            ow_p[r] = (ow[r] / d) * 2.5f;
        }
    }
}

extern "C" void kernel_launch(void* const* d_in, const int* in_sizes, int n_in,
                              void* d_out, int out_size, void* d_ws, size_t ws_size,
                              hipStream_t stream)
{
    const float* hs   = (const float*)d_in[0];   // [8192, 7168]
    const float* W    = (const float*)d_in[1];   // [256, 7168]
    const float* b    = (const float*)d_in[2];   // [256]
    const float* corr = (const float*)d_in[3];   // [256]
    float* out = (float*)d_out;                  // 65536 idx-as-float + 65536 weights
    float* logits = (float*)d_ws;                // 8 MB fp32 accumulator

    // zero the logits accumulator (split-K atomics land here)
    hipMemsetAsync(logits, 0, (size_t)LOGITS_F32 * sizeof(float), stream);

    if (ws_size >= (size_t)WS_NEEDED) {
        // fast path: precompute fragment-ordered f16 hi/lo W, then
        // barrier-free LDS-free MFMA GEMM
        _Float16* whi = (_Float16*)((char*)d_ws + (size_t)LOGITS_F32 * 4);
        _Float16* wlo = whi + (size_t)W16_PLANE_F16;
        conv_w_kernel<<<896, 256, 0, stream>>>(W, whi, wlo);
        router_gemm_v4<<<512, 256, 0, stream>>>(hs, whi, wlo, logits);
    } else {
        // fallback: proven v2 structure
        dim3 g1(FB_KS, NTOK / FB_BM);
        router_gemm_fb<<<g1, 512, 0, stream>>>(hs, W, logits);
    }
    router_topk_kernel<<<NTOK / 4, 256, 0, stream>>>(logits, b, corr, out);
}

// Round 4
// 423.580 us; speedup vs baseline: 1.3091x; 1.0095x over previous
//
#include <hip/hip_runtime.h>
#include <math.h>

#define HDIM 7168
#define NEXP 256
#define NTOK 8192

// ---- v5 geometry ----
#define KS 8                  // k-splits (== XCD count)
#define KSTEPS 224            // HDIM/32 global k-steps
#define KCH (HDIM / KS)       // 896 source-k per block
#define NR (KCH / 32)         // 28 k-steps per block
#define BM 128                // block m rows
#define NTILES 16             // NEXP/16 n-tiles

#define LOGITS_F32 (NTOK * NEXP)                  // 8 MB fp32
#define W16_PLANE_F16 (NTILES * KSTEPS * 512)     // 1,835,008 f16 = 3.5 MB
#define WS_NEEDED (LOGITS_F32 * 4 + 2 * W16_PLANE_F16 * 2)   // 15,728,640 B

typedef _Float16 f16x8 __attribute__((ext_vector_type(8)));
typedef float f32x4 __attribute__((ext_vector_type(4)));

__device__ __forceinline__ f16x8 hi8(float4 u, float4 v) {
    f16x8 h;
    h[0] = (_Float16)u.x; h[1] = (_Float16)u.y; h[2] = (_Float16)u.z; h[3] = (_Float16)u.w;
    h[4] = (_Float16)v.x; h[5] = (_Float16)v.y; h[6] = (_Float16)v.z; h[7] = (_Float16)v.w;
    return h;
}
__device__ __forceinline__ f16x8 lo8(float4 u, float4 v, f16x8 h) {
    f16x8 l;
    l[0] = (_Float16)(u.x - (float)h[0]); l[1] = (_Float16)(u.y - (float)h[1]);
    l[2] = (_Float16)(u.z - (float)h[2]); l[3] = (_Float16)(u.w - (float)h[3]);
    l[4] = (_Float16)(v.x - (float)h[4]); l[5] = (_Float16)(v.y - (float)h[5]);
    l[6] = (_Float16)(v.z - (float)h[6]); l[7] = (_Float16)(v.w - (float)h[7]);
    return l;
}

// async global->LDS, 16B per lane: LDS dest = wave-uniform base + lane*16,
// global src = per-lane address (guide m97/m104).
__device__ __forceinline__ void glds16(const _Float16* g, _Float16* l) {
    __builtin_amdgcn_global_load_lds(
        (const __attribute__((address_space(1))) unsigned int*)g,
        (__attribute__((address_space(3))) unsigned int*)l,
        16, 0, 0);
}

// ---------------------------------------------------------------------------
// Kernel 0: convert W (256x7168 fp32) -> f16 hi/lo planes in MFMA-FRAGMENT
// order. Frag f = nt*KSTEPS + ksi: element [lane][j] =
// W[nt*16 + (lane&15)][ksi*32 + (lane>>4)*8 + j] * 256.  (unchanged from v4)
// ---------------------------------------------------------------------------
__global__ __launch_bounds__(256)
void conv_w_kernel(const float* __restrict__ W,
                   _Float16* __restrict__ whi,
                   _Float16* __restrict__ wlo)
{
    const int t = blockIdx.x * 256 + threadIdx.x;
    const int lane = t & 63;
    const int f = t >> 6;
    const int ksi = f % KSTEPS;
    const int nt  = f / KSTEPS;
    const int n = nt * 16 + (lane & 15);
    const int k = ksi * 32 + (lane >> 4) * 8;
    const float* src = W + (size_t)n * HDIM + k;
    float4 u = *(const float4*)(src + 0);
    float4 v = *(const float4*)(src + 4);
    u.x *= 256.0f; u.y *= 256.0f; u.z *= 256.0f; u.w *= 256.0f;
    v.x *= 256.0f; v.y *= 256.0f; v.z *= 256.0f; v.w *= 256.0f;
    f16x8 h = hi8(u, v);
    f16x8 l = lo8(u, v, h);
    *(f16x8*)&whi[(size_t)f * 512 + lane * 8] = h;
    *(f16x8*)&wlo[(size_t)f * 512 + lane * 8] = l;
}

// ---------------------------------------------------------------------------
// Kernel 1 (v5): m97-pattern GEMM. logits = hs @ W^T, 3-product f16 split.
// Fixes v2-v4's universal disease: load results no longer live in VGPRs.
//   B: global_load_lds from fragment-ordered planes (1 KB/frag, linear LDS,
//      zero staging registers, drained once per k-step at the barrier).
//   A: fp32 global->reg (1 float4-pair/thread), hi/lo convert, ds_write into
//      fragment-ordered LDS (wave w writes m-tile w's frag: contiguous 1 KB).
//   Double-buffered; ONE barrier per k-step; prefetch issued at step top,
//   consumed next step (48 MFMA/wave covers latency).
// Block 128m x 256n, 512 thr, 8 waves (2m x 4n) of 64x64; acc[4][4]=64 VGPR.
// LDS 96 KB -> 1 block/CU. Grid (KS=8, 64) = 512 blocks = 2 passes;
// blockIdx.x = k-slice = XCD id -> 896 KB W-slice per XCD L2.
// ---------------------------------------------------------------------------
__global__ __launch_bounds__(512, 2)
void router_gemm_v5(const float* __restrict__ hs,
                    const _Float16* __restrict__ whi,
                    const _Float16* __restrict__ wlo,
                    float* __restrict__ logits)
{
    __shared__ __align__(16) _Float16 Bl[2][32 * 512];   // 64 KB
    __shared__ __align__(16) _Float16 Al[2][16 * 512];   // 32 KB

    const int tid  = threadIdx.x;
    const int lane = tid & 63;
    const int wave = tid >> 6;            // 0..7
    const int ksb  = blockIdx.x;          // 0..7 (== XCD id)
    const int bm   = blockIdx.y * BM;
    const int ks0  = ksb * NR;            // first global k-step
    const int kb   = ksb * KCH;

    const int wm = (wave >> 2) << 6;      // 0 / 64
    const int wn = (wave & 3) << 6;       // 0 / 64 / 128 / 192
    const int fm = lane & 15;
    const int quad = lane >> 4;
    const int mt0 = wm >> 4;              // 0 or 4
    const int nt0 = wn >> 4;              // 0,4,8,12

    // B glds: wave stages frags F = 4*wave .. 4*wave+3, F = nt*2 + (hi/lo)
    const int F0 = wave * 4;

    // A staging: thread -> row tid>>2 (0..127), k-quad tid&3
    const int s_row = tid >> 2;
    const int s_q   = tid & 3;
    const float* Ap = hs + (size_t)(bm + s_row) * HDIM + kb + s_q * 8;
    const int s_imt = s_row >> 4;                          // == wave of writer
    const int s_eb  = ((s_q << 4) + (s_row & 15)) << 3;    // frag element base

    f32x4 acc[4][4];
#pragma unroll
    for (int i = 0; i < 4; i++)
#pragma unroll
        for (int j = 0; j < 4; j++) acc[i][j] = (f32x4)0.0f;

    // ---- prologue: stage step 0 into buffer 0 ----
#pragma unroll
    for (int f = 0; f < 4; f++) {
        const int F = F0 + f;
        const int nt = F >> 1;
        const _Float16* plane = (F & 1) ? wlo : whi;
        glds16(plane + ((size_t)nt * KSTEPS + ks0) * 512 + lane * 8,
               &Bl[0][F * 512]);
    }
    {
        float4 u = *(const float4*)(Ap + 0);
        float4 v = *(const float4*)(Ap + 4);
        f16x8 h = hi8(u, v);
        f16x8 l = lo8(u, v, h);
        *(f16x8*)&Al[0][(s_imt * 2 + 0) * 512 + s_eb] = h;
        *(f16x8*)&Al[0][(s_imt * 2 + 1) * 512 + s_eb] = l;
    }
    __syncthreads();

#pragma unroll 2
    for (int r = 0; r < NR; ++r) {
        const int cur = r & 1;
        float4 u, v;
        // ---- prefetch step r+1 (glds B -> other buffer; A -> regs) ----
        if (r + 1 < NR) {
#pragma unroll
            for (int f = 0; f < 4; f++) {
                const int F = F0 + f;
                const int nt = F >> 1;
                const _Float16* plane = (F & 1) ? wlo : whi;
                glds16(plane + ((size_t)nt * KSTEPS + ks0 + r + 1) * 512 + lane * 8,
                       &Bl[cur ^ 1][F * 512]);
            }
            const float* An = Ap + (r + 1) * 32;
            u = *(const float4*)(An + 0);
            v = *(const float4*)(An + 4);
        }
        // ---- fragment reads from current buffers (lane*16B, linear) ----
        f16x8 af[4], al_[4], bh[4], bl_[4];
#pragma unroll
        for (int im = 0; im < 4; im++) {
            af[im]  = *(const f16x8*)&Al[cur][((mt0 + im) * 2 + 0) * 512 + lane * 8];
            al_[im] = *(const f16x8*)&Al[cur][((mt0 + im) * 2 + 1) * 512 + lane * 8];
        }
#pragma unroll
        for (int in_ = 0; in_ < 4; in_++) {
            bh[in_]  = *(const f16x8*)&Bl[cur][((nt0 + in_) * 2 + 0) * 512 + lane * 8];
            bl_[in_] = *(const f16x8*)&Bl[cur][((nt0 + in_) * 2 + 1) * 512 + lane * 8];
        }
        // ---- 48 MFMA: P1 Ah*Bh, P2 Ah*Bl, P3 Al*Bh ----
#pragma unroll
        for (int im = 0; im < 4; im++)
#pragma unroll
            for (int in_ = 0; in_ < 4; in_++)
                acc[im][in_] = __builtin_amdgcn_mfma_f32_16x16x32_f16(af[im], bh[in_], acc[im][in_], 0, 0, 0);
#pragma unroll
        for (int im = 0; im < 4; im++)
#pragma unroll
            for (int in_ = 0; in_ < 4; in_++)
                acc[im][in_] = __builtin_amdgcn_mfma_f32_16x16x32_f16(af[im], bl_[in_], acc[im][in_], 0, 0, 0);
#pragma unroll
        for (int im = 0; im < 4; im++)
#pragma unroll
            for (int in_ = 0; in_ < 4; in_++)
                acc[im][in_] = __builtin_amdgcn_mfma_f32_16x16x32_f16(al_[im], bh[in_], acc[im][in_], 0, 0, 0);
        // ---- stage next-step A into the other buffer ----
        if (r + 1 < NR) {
            f16x8 h = hi8(u, v);
            f16x8 l = lo8(u, v, h);
            *(f16x8*)&Al[cur ^ 1][(s_imt * 2 + 0) * 512 + s_eb] = h;
            *(f16x8*)&Al[cur ^ 1][(s_imt * 2 + 1) * 512 + s_eb] = l;
        }
        __syncthreads();   // drains glds (vmcnt) + ds writes (lgkmcnt)
    }

    // ---- epilogue: undo x256 on B, combine K-splits via atomics ----
#pragma unroll
    for (int im = 0; im < 4; im++) {
#pragma unroll
        for (int in_ = 0; in_ < 4; in_++) {
            const int n = wn + in_ * 16 + fm;
#pragma unroll
            for (int rr = 0; rr < 4; rr++) {
                const int m = bm + wm + im * 16 + quad * 4 + rr;
                unsafeAtomicAdd(&logits[(size_t)m * NEXP + n], acc[im][in_][rr] * 0.00390625f);
            }
        }
    }
}

// ---------------------------------------------------------------------------
// Fallback GEMM (v2, proven absmax=0) used when ws_size < WS_NEEDED.
// ---------------------------------------------------------------------------
#define FB_BM 128
#define FB_KS 4
#define FB_KCH (HDIM / FB_KS)
#define FB_NR (FB_KCH / 32)
#define FB_PITCH 72

__global__ __launch_bounds__(512, 2)
void router_gemm_fb(const float* __restrict__ hs,
                    const float* __restrict__ W,
                    float* __restrict__ logits)
{
    __shared__ __align__(16) _Float16 Alds[2][FB_BM * FB_PITCH];

    const int tid  = threadIdx.x;
    const int lane = tid & 63;
    const int wave = tid >> 6;
    const int kb = blockIdx.x * FB_KCH;
    const int bm = blockIdx.y * FB_BM;

    const int wm = (wave >> 2) << 6;
    const int wc = wave & 3;
    const int fm = lane & 15;
    const int quad = lane >> 4;

    const int arow = tid >> 2;
    const int akh  = (tid & 3) << 3;
    const float* Ap = hs + (size_t)(bm + arow) * HDIM + kb + akh;
    const float* Bp = W + (size_t)(wc * 64 + fm) * HDIM + kb + quad * 8;

    f32x4 acc[4][4];
#pragma unroll
    for (int i = 0; i < 4; i++)
#pragma unroll
        for (int j = 0; j < 4; j++) acc[i][j] = (f32x4)0.0f;

    float4 a0 = *(const float4*)(Ap + 0);
    float4 a1 = *(const float4*)(Ap + 4);
    float4 bu[4], bv[4];
#pragma unroll
    for (int i = 0; i < 4; i++) {
        const float* q = Bp + (size_t)i * (16 * HDIM);
        bu[i] = *(const float4*)(q + 0);
        bv[i] = *(const float4*)(q + 4);
    }
    {
        f16x8 h = hi8(a0, a1);
        f16x8 l = lo8(a0, a1, h);
        *(f16x8*)&Alds[0][arow * FB_PITCH + akh]      = h;
        *(f16x8*)&Alds[0][arow * FB_PITCH + 32 + akh] = l;
    }
    __syncthreads();

#pragma unroll 2
    for (int r = 0; r < FB_NR; ++r) {
        const int cur = r & 1;
        f16x8 bh[4], bl[4];
#pragma unroll
        for (int i = 0; i < 4; i++) {
            float4 s0 = make_float4(bu[i].x * 256.0f, bu[i].y * 256.0f,
                                    bu[i].z * 256.0f, bu[i].w * 256.0f);
            float4 s1 = make_float4(bv[i].x * 256.0f, bv[i].y * 256.0f,
                                    bv[i].z * 256.0f, bv[i].w * 256.0f);
            bh[i] = hi8(s0, s1);
            bl[i] = lo8(s0, s1, bh[i]);
        }
        if (r + 1 < FB_NR) {
            const float* An = Ap + (r + 1) * 32;
            a0 = *(const float4*)(An + 0);
            a1 = *(const float4*)(An + 4);
            const float* Bn = Bp + (r + 1) * 32;
#pragma unroll
            for (int i = 0; i < 4; i++) {
                const float* q = Bn + (size_t)i * (16 * HDIM);
                bu[i] = *(const float4*)(q + 0);
                bv[i] = *(const float4*)(q + 4);
            }
        }
        f16x8 af[4], alo[4];
#pragma unroll
        for (int im = 0; im < 4; im++) {
            const int off = (wm + im * 16 + fm) * FB_PITCH + quad * 8;
            af[im]  = *(const f16x8*)&Alds[cur][off];
            alo[im] = *(const f16x8*)&Alds[cur][off + 32];
        }
#pragma unroll
        for (int im = 0; im < 4; im++)
#pragma unroll
            for (int in_ = 0; in_ < 4; in_++)
                acc[im][in_] = __builtin_amdgcn_mfma_f32_16x16x32_f16(af[im], bh[in_], acc[im][in_], 0, 0, 0);
#pragma unroll
        for (int im = 0; im < 4; im++)
#pragma unroll
            for (int in_ = 0; in_ < 4; in_++)
                acc[im][in_] = __builtin_amdgcn_mfma_f32_16x16x32_f16(af[im], bl[in_], acc[im][in_], 0, 0, 0);
#pragma unroll
        for (int im = 0; im < 4; im++)
#pragma unroll
            for (int in_ = 0; in_ < 4; in_++)
                acc[im][in_] = __builtin_amdgcn_mfma_f32_16x16x32_f16(alo[im], bh[in_], acc[im][in_], 0, 0, 0);
        if (r + 1 < FB_NR) {
            f16x8 h = hi8(a0, a1);
            f16x8 l = lo8(a0, a1, h);
            *(f16x8*)&Alds[cur ^ 1][arow * FB_PITCH + akh]      = h;
            *(f16x8*)&Alds[cur ^ 1][arow * FB_PITCH + 32 + akh] = l;
        }
        __syncthreads();
    }

#pragma unroll
    for (int im = 0; im < 4; im++) {
#pragma unroll
        for (int in_ = 0; in_ < 4; in_++) {
            const int n = wc * 64 + in_ * 16 + fm;
#pragma unroll
            for (int rr = 0; rr < 4; rr++) {
                const int m = bm + wm + im * 16 + quad * 4 + rr;
                unsafeAtomicAdd(&logits[(size_t)m * NEXP + n], acc[im][in_][rr] * 0.00390625f);
            }
        }
    }
}

// ---------------------------------------------------------------------------
// Kernel 2: one wave per token. lane l holds experts 4l..4l+3.
// Replicates jax.lax.top_k semantics exactly. (Unchanged.)
// ---------------------------------------------------------------------------
__global__ __launch_bounds__(256)
void router_topk_kernel(const float* __restrict__ logits,
                        const float* __restrict__ bias,
                        const float* __restrict__ corr,
                        float* __restrict__ out)
{
    const int lane = threadIdx.x & 63;
    const int wave = threadIdx.x >> 6;
    const int t = blockIdx.x * 4 + wave;
    const float* row = logits + (size_t)t * NEXP;
    const int e0 = lane << 2;

    float4 lg = *(const float4*)(row + e0);
    float4 bb = *(const float4*)(bias + e0);
    float4 cc = *(const float4*)(corr + e0);

    float xs[4] = {lg.x + bb.x, lg.y + bb.y, lg.z + bb.z, lg.w + bb.w};
    float cs[4] = {cc.x, cc.y, cc.z, cc.w};
    float s[4], sc[4], mv[4];
#pragma unroll
    for (int i = 0; i < 4; i++) {
        s[i] = 1.0f / (1.0f + expf(-xs[i]));
        sc[i] = s[i] + cs[i];
    }

    float m1 = fmaxf(sc[0], sc[1]);
    float m2 = fminf(sc[0], sc[1]);
    if (sc[2] > m1) { m2 = m1; m1 = sc[2]; } else { m2 = fmaxf(m2, sc[2]); }
    if (sc[3] > m1) { m2 = m1; m1 = sc[3]; } else { m2 = fmaxf(m2, sc[3]); }
#pragma unroll
    for (int off = 1; off <= 4; off <<= 1) {
        float o1 = __shfl_xor(m1, off);
        float o2 = __shfl_xor(m2, off);
        float hi = fmaxf(m1, o1);
        float lo = fminf(m1, o1);
        m1 = hi;
        m2 = fmaxf(lo, fmaxf(m2, o2));
    }
    const float gscore = m1 + m2;

    float gs[8];
#pragma unroll
    for (int j = 0; j < 8; j++) gs[j] = __shfl(gscore, j << 3);
    const int g = lane >> 3;
    int rank = 0;
#pragma unroll
    for (int j = 0; j < 8; j++)
        rank += ((gs[j] > gs[g]) || ((gs[j] == gs[g]) && (j < g))) ? 1 : 0;
    const bool sel = (rank < 4);

#pragma unroll
    for (int i = 0; i < 4; i++) mv[i] = sel ? sc[i] : 0.0f;

    int oidx[8];
    float ow[8];
    float wsum = 0.0f;
#pragma unroll
    for (int r = 0; r < 8; r++) {
        float bv = mv[0]; int bi = e0;
        if (mv[1] > bv) { bv = mv[1]; bi = e0 + 1; }
        if (mv[2] > bv) { bv = mv[2]; bi = e0 + 2; }
        if (mv[3] > bv) { bv = mv[3]; bi = e0 + 3; }
#pragma unroll
        for (int off = 32; off >= 1; off >>= 1) {
            float ov = __shfl_xor(bv, off);
            int oi = __shfl_xor(bi, off);
            if ((ov > bv) || ((ov == bv) && (oi < bi))) { bv = ov; bi = oi; }
        }
        const int wl = bi >> 2;
        const int slot = bi & 3;
        float sraw = (slot == 0) ? s[0] : (slot == 1) ? s[1] : (slot == 2) ? s[2] : s[3];
        sraw = __shfl(sraw, wl);
        if (lane == wl) {
            if (slot == 0) mv[0] = -1e30f;
            else if (slot == 1) mv[1] = -1e30f;
            else if (slot == 2) mv[2] = -1e30f;
            else mv[3] = -1e30f;
        }
        oidx[r] = bi;
        ow[r] = sraw;
        wsum += sraw;
    }

    if (lane == 0) {
        const float d = wsum + 1e-20f;
        float* oi_p = out + (size_t)t * 8;
        float* ow_p = out + (size_t)NTOK * 8 + (size_t)t * 8;
#pragma unroll
        for (int r = 0; r < 8; r++) {
            oi_p[r] = (float)oidx[r];
            ow_p[r] = (ow[r] / d) * 2.5f;
        }
    }
}

extern "C" void kernel_launch(void* const* d_in, const int* in_sizes, int n_in,
                              void* d_out, int out_size, void* d_ws, size_t ws_size,
                              hipStream_t stream)
{
    const float* hs   = (const float*)d_in[0];   // [8192, 7168]
    const float* W    = (const float*)d_in[1];   // [256, 7168]
    const float* b    = (const float*)d_in[2];   // [256]
    const float* corr = (const float*)d_in[3];   // [256]
    float* out = (float*)d_out;                  // 65536 idx-as-float + 65536 weights
    float* logits = (float*)d_ws;                // 8 MB fp32 accumulator

    // zero the logits accumulator (split-K atomics land here)
    hipMemsetAsync(logits, 0, (size_t)LOGITS_F32 * sizeof(float), stream);

    if (ws_size >= (size_t)WS_NEEDED) {
        _Float16* whi = (_Float16*)((char*)d_ws + (size_t)LOGITS_F32 * 4);
        _Float16* wlo = whi + (size_t)W16_PLANE_F16;
        conv_w_kernel<<<896, 256, 0, stream>>>(W, whi, wlo);
        dim3 g1(KS, NTOK / BM);                  // (8, 64) -> 512 blocks
        router_gemm_v5<<<g1, 512, 0, stream>>>(hs, whi, wlo, logits);
    } else {
        dim3 g1(FB_KS, NTOK / FB_BM);
        router_gemm_fb<<<g1, 512, 0, stream>>>(hs, W, logits);
    }
    router_topk_kernel<<<NTOK / 4, 256, 0, stream>>>(logits, b, corr, out);
}

// Round 5
// 419.895 us; speedup vs baseline: 1.3206x; 1.0088x over previous
//
#include <hip/hip_runtime.h>
#include <math.h>

#define HDIM 7168
#define NEXP 256
#define NTOK 8192

// ---- v6 geometry ----
#define KS 8                  // k-splits (== XCD count)
#define KSTEPS 224            // HDIM/32 global k-steps
#define KCH (HDIM / KS)       // 896 source-k per block
#define NR (KCH / 32)         // 28 k-steps per block
#define BM 256                // block m rows
#define NTILES 16             // NEXP/16 n-tiles

#define LOGITS_F32 (NTOK * NEXP)                  // 8 MB fp32
#define W16_PLANE_F16 (NTILES * KSTEPS * 512)     // 1,835,008 f16 = 3.5 MB
#define WS_NEEDED (LOGITS_F32 * 4 + 2 * W16_PLANE_F16 * 2)   // 15,728,640 B

typedef _Float16 f16x8 __attribute__((ext_vector_type(8)));
typedef float f32x4 __attribute__((ext_vector_type(4)));

__device__ __forceinline__ f16x8 hi8(float4 u, float4 v) {
    f16x8 h;
    h[0] = (_Float16)u.x; h[1] = (_Float16)u.y; h[2] = (_Float16)u.z; h[3] = (_Float16)u.w;
    h[4] = (_Float16)v.x; h[5] = (_Float16)v.y; h[6] = (_Float16)v.z; h[7] = (_Float16)v.w;
    return h;
}
__device__ __forceinline__ f16x8 lo8(float4 u, float4 v, f16x8 h) {
    f16x8 l;
    l[0] = (_Float16)(u.x - (float)h[0]); l[1] = (_Float16)(u.y - (float)h[1]);
    l[2] = (_Float16)(u.z - (float)h[2]); l[3] = (_Float16)(u.w - (float)h[3]);
    l[4] = (_Float16)(v.x - (float)h[4]); l[5] = (_Float16)(v.y - (float)h[5]);
    l[6] = (_Float16)(v.z - (float)h[6]); l[7] = (_Float16)(v.w - (float)h[7]);
    return l;
}

// async global->LDS, 16B per lane: LDS dest = wave-uniform base + lane*16.
__device__ __forceinline__ void glds16(const _Float16* g, _Float16* l) {
    __builtin_amdgcn_global_load_lds(
        (const __attribute__((address_space(1))) unsigned int*)g,
        (__attribute__((address_space(3))) unsigned int*)l,
        16, 0, 0);
}

// ---------------------------------------------------------------------------
// Kernel 0: W (256x7168 fp32) -> f16 hi/lo planes in MFMA-fragment order.
// Frag f = nt*KSTEPS + ksi: [lane][j] = W[nt*16+(lane&15)][ksi*32+(lane>>4)*8+j]*256.
// (unchanged, proven)
// ---------------------------------------------------------------------------
__global__ __launch_bounds__(256)
void conv_w_kernel(const float* __restrict__ W,
                   _Float16* __restrict__ whi,
                   _Float16* __restrict__ wlo)
{
    const int t = blockIdx.x * 256 + threadIdx.x;
    const int lane = t & 63;
    const int f = t >> 6;
    const int ksi = f % KSTEPS;
    const int nt  = f / KSTEPS;
    const int n = nt * 16 + (lane & 15);
    const int k = ksi * 32 + (lane >> 4) * 8;
    const float* src = W + (size_t)n * HDIM + k;
    float4 u = *(const float4*)(src + 0);
    float4 v = *(const float4*)(src + 4);
    u.x *= 256.0f; u.y *= 256.0f; u.z *= 256.0f; u.w *= 256.0f;
    v.x *= 256.0f; v.y *= 256.0f; v.z *= 256.0f; v.w *= 256.0f;
    f16x8 h = hi8(u, v);
    f16x8 l = lo8(u, v, h);
    *(f16x8*)&whi[(size_t)f * 512 + lane * 8] = h;
    *(f16x8*)&wlo[(size_t)f * 512 + lane * 8] = l;
}

// ---------------------------------------------------------------------------
// Kernel 1 (v6): counted-vmcnt pipelined GEMM (T3/T4 pattern, no vmcnt(0)
// drain in the main loop). logits = hs @ W^T, 3-product f16 split.
//
// v5 post-mortem: __syncthreads => vmcnt(0) drain per step serialized
// MFMA(1862cy) + LDS(2460cy) + A-HBM(1600cy) + B-L2(750cy) ~= 7400cy/step.
// v6 removes each serializer:
//   * A never goes through LDS: each lane loads exactly its fragment's 8
//     fp32 (row fm, k quad*8..+7) from global; 4 quads cover one full 128B
//     line => line-coalesced; x2 reuse across n-wave pairs is L1-absorbed.
//     Converted hi/lo in-reg. A prefetched 1 step ahead (regs, 32 VGPR).
//   * B: glds into 3x32KB LDS ring, issued 2 steps ahead. Pre-barrier
//     s_waitcnt vmcnt(12) [tail: 8] drains exactly through B(r) while
//     B(r+1),B(r+2),A(r+1) stay IN FLIGHT across the raw s_barrier.
//     Each wave drains its own loads, then s_barrier makes it collective.
//     glds for buf[(r+2)%3] issues post-barrier, after all readers of that
//     buffer (step r-1) crossed => no overwrite race.
//   * sched_barrier(0) pins the issue cluster above the MFMA block.
// Tile: 256m x 256n, BK=32, 8 waves of 64x128 (4m x 2n). acc[4][8]=128 VGPR.
// Grid (KS=8, 32) = 256 blocks = exactly 1/CU single pass; blockIdx.x =
// k-slice = XCD id (896 KB W-slice L2-resident). Split-K via atomics.
// ---------------------------------------------------------------------------
__global__ __launch_bounds__(512, 2)
void router_gemm_v6(const float* __restrict__ hs,
                    const _Float16* __restrict__ whi,
                    const _Float16* __restrict__ wlo,
                    float* __restrict__ logits)
{
    __shared__ __align__(16) _Float16 Bbuf[3][32 * 512];   // 3 x 32 KB

    const int tid  = threadIdx.x;
    const int lane = tid & 63;
    const int wave = tid >> 6;            // 0..7
    const int ksb  = blockIdx.x;          // 0..7 (== XCD id)
    const int bm   = blockIdx.y * BM;
    const int ks0  = ksb * NR;            // first global k-step
    const int kb   = ksb * KCH;

    const int wm  = (wave >> 1) << 6;     // m band: 0/64/128/192
    const int wn2 = wave & 1;             // n half: 0/1 (128 cols each)
    const int fm  = lane & 15;
    const int quad = lane >> 4;
    const int F0 = wave * 4;              // this wave's staged frag ids

    // A fragment source pointers: lane holds A[wm+im*16+fm][k: quad*8..+7]
    const float* ap[4];
#pragma unroll
    for (int im = 0; im < 4; im++)
        ap[im] = hs + (size_t)(bm + wm + im * 16 + fm) * HDIM + kb + quad * 8;

    f32x4 acc[4][8];
#pragma unroll
    for (int i = 0; i < 4; i++)
#pragma unroll
        for (int j = 0; j < 8; j++) acc[i][j] = (f32x4)0.0f;

    // ---- prologue: issue B(0), B(1), A(0)  (queue: 4+4+8 = 16) ----
#pragma unroll
    for (int f = 0; f < 4; f++) {
        const int F = F0 + f;
        const int nt = F >> 1;
        const _Float16* plane = (F & 1) ? wlo : whi;
        glds16(plane + ((size_t)nt * KSTEPS + ks0 + 0) * 512 + lane * 8,
               &Bbuf[0][F * 512]);
    }
#pragma unroll
    for (int f = 0; f < 4; f++) {
        const int F = F0 + f;
        const int nt = F >> 1;
        const _Float16* plane = (F & 1) ? wlo : whi;
        glds16(plane + ((size_t)nt * KSTEPS + ks0 + 1) * 512 + lane * 8,
               &Bbuf[1][F * 512]);
    }
    float4 a0[4], a1[4];
#pragma unroll
    for (int im = 0; im < 4; im++) {
        a0[im] = *(const float4*)(ap[im] + 0);
        a1[im] = *(const float4*)(ap[im] + 4);
    }

#pragma unroll 1
    for (int r = 0; r < NR; ++r) {
        // ---- own-load drain: leave B(r+1)+A(r) [+B(r+2) not yet issued]
        //      in flight; drains exactly through B(r). Tail: only A(r) left.
        if (r + 1 < NR) {
            asm volatile("s_waitcnt vmcnt(12)" ::: "memory");
        } else {
            asm volatile("s_waitcnt vmcnt(8)" ::: "memory");
        }
        asm volatile("s_barrier" ::: "memory");   // buf[r%3] collectively ready

        // ---- issue B(r+2) into the ring slot readers just vacated ----
        if (r + 2 < NR) {
            _Float16* dst = &Bbuf[(r + 2) % 3][0];
#pragma unroll
            for (int f = 0; f < 4; f++) {
                const int F = F0 + f;
                const int nt = F >> 1;
                const _Float16* plane = (F & 1) ? wlo : whi;
                glds16(plane + ((size_t)nt * KSTEPS + ks0 + r + 2) * 512 + lane * 8,
                       dst + F * 512);
            }
        }
        // ---- convert A(r) in-reg (compiler auto-waits only A's vmcnt) ----
        f16x8 af[4], al_[4];
#pragma unroll
        for (int im = 0; im < 4; im++) {
            af[im]  = hi8(a0[im], a1[im]);
            al_[im] = lo8(a0[im], a1[im], af[im]);
        }
        // ---- issue A(r+1) into the now-free regs ----
        if (r + 1 < NR) {
#pragma unroll
            for (int im = 0; im < 4; im++) {
                const float* p = ap[im] + (size_t)(r + 1) * 32;
                a0[im] = *(const float4*)(p + 0);
                a1[im] = *(const float4*)(p + 4);
            }
        }
        __builtin_amdgcn_sched_barrier(0);   // loads stay above the MFMA block

        // ---- 96 MFMA over this 32-k step (8 ntiles x 4 mtiles x 3 prod) ----
        const _Float16* Bc = &Bbuf[r % 3][0];
#pragma unroll
        for (int j = 0; j < 8; j++) {
            const int ntl = ((wn2 * 8 + j) << 1);
            f16x8 bh = *(const f16x8*)&Bc[(ntl + 0) * 512 + lane * 8];
            f16x8 bl = *(const f16x8*)&Bc[(ntl + 1) * 512 + lane * 8];
#pragma unroll
            for (int im = 0; im < 4; im++)
                acc[im][j] = __builtin_amdgcn_mfma_f32_16x16x32_f16(af[im], bh, acc[im][j], 0, 0, 0);
#pragma unroll
            for (int im = 0; im < 4; im++)
                acc[im][j] = __builtin_amdgcn_mfma_f32_16x16x32_f16(af[im], bl, acc[im][j], 0, 0, 0);
#pragma unroll
            for (int im = 0; im < 4; im++)
                acc[im][j] = __builtin_amdgcn_mfma_f32_16x16x32_f16(al_[im], bh, acc[im][j], 0, 0, 0);
        }
    }

    // ---- epilogue: undo x256 on B, combine K-splits via atomics ----
#pragma unroll
    for (int im = 0; im < 4; im++) {
#pragma unroll
        for (int j = 0; j < 8; j++) {
            const int n = wn2 * 128 + j * 16 + fm;
#pragma unroll
            for (int rr = 0; rr < 4; rr++) {
                const int m = bm + wm + im * 16 + quad * 4 + rr;
                unsafeAtomicAdd(&logits[(size_t)m * NEXP + n], acc[im][j][rr] * 0.00390625f);
            }
        }
    }
}

// ---------------------------------------------------------------------------
// Fallback GEMM (v2, proven absmax=0) used when ws_size < WS_NEEDED.
// ---------------------------------------------------------------------------
#define FB_BM 128
#define FB_KS 4
#define FB_KCH (HDIM / FB_KS)
#define FB_NR (FB_KCH / 32)
#define FB_PITCH 72

__global__ __launch_bounds__(512, 2)
void router_gemm_fb(const float* __restrict__ hs,
                    const float* __restrict__ W,
                    float* __restrict__ logits)
{
    __shared__ __align__(16) _Float16 Alds[2][FB_BM * FB_PITCH];

    const int tid  = threadIdx.x;
    const int lane = tid & 63;
    const int wave = tid >> 6;
    const int kb = blockIdx.x * FB_KCH;
    const int bm = blockIdx.y * FB_BM;

    const int wm = (wave >> 2) << 6;
    const int wc = wave & 3;
    const int fm = lane & 15;
    const int quad = lane >> 4;

    const int arow = tid >> 2;
    const int akh  = (tid & 3) << 3;
    const float* Ap = hs + (size_t)(bm + arow) * HDIM + kb + akh;
    const float* Bp = W + (size_t)(wc * 64 + fm) * HDIM + kb + quad * 8;

    f32x4 acc[4][4];
#pragma unroll
    for (int i = 0; i < 4; i++)
#pragma unroll
        for (int j = 0; j < 4; j++) acc[i][j] = (f32x4)0.0f;

    float4 a0 = *(const float4*)(Ap + 0);
    float4 a1 = *(const float4*)(Ap + 4);
    float4 bu[4], bv[4];
#pragma unroll
    for (int i = 0; i < 4; i++) {
        const float* q = Bp + (size_t)i * (16 * HDIM);
        bu[i] = *(const float4*)(q + 0);
        bv[i] = *(const float4*)(q + 4);
    }
    {
        f16x8 h = hi8(a0, a1);
        f16x8 l = lo8(a0, a1, h);
        *(f16x8*)&Alds[0][arow * FB_PITCH + akh]      = h;
        *(f16x8*)&Alds[0][arow * FB_PITCH + 32 + akh] = l;
    }
    __syncthreads();

#pragma unroll 2
    for (int r = 0; r < FB_NR; ++r) {
        const int cur = r & 1;
        f16x8 bh[4], bl[4];
#pragma unroll
        for (int i = 0; i < 4; i++) {
            float4 s0 = make_float4(bu[i].x * 256.0f, bu[i].y * 256.0f,
                                    bu[i].z * 256.0f, bu[i].w * 256.0f);
            float4 s1 = make_float4(bv[i].x * 256.0f, bv[i].y * 256.0f,
                                    bv[i].z * 256.0f, bv[i].w * 256.0f);
            bh[i] = hi8(s0, s1);
            bl[i] = lo8(s0, s1, bh[i]);
        }
        if (r + 1 < FB_NR) {
            const float* An = Ap + (r + 1) * 32;
            a0 = *(const float4*)(An + 0);
            a1 = *(const float4*)(An + 4);
            const float* Bn = Bp + (r + 1) * 32;
#pragma unroll
            for (int i = 0; i < 4; i++) {
                const float* q = Bn + (size_t)i * (16 * HDIM);
                bu[i] = *(const float4*)(q + 0);
                bv[i] = *(const float4*)(q + 4);
            }
        }
        f16x8 af[4], alo[4];
#pragma unroll
        for (int im = 0; im < 4; im++) {
            const int off = (wm + im * 16 + fm) * FB_PITCH + quad * 8;
            af[im]  = *(const f16x8*)&Alds[cur][off];
            alo[im] = *(const f16x8*)&Alds[cur][off + 32];
        }
#pragma unroll
        for (int im = 0; im < 4; im++)
#pragma unroll
            for (int in_ = 0; in_ < 4; in_++)
                acc[im][in_] = __builtin_amdgcn_mfma_f32_16x16x32_f16(af[im], bh[in_], acc[im][in_], 0, 0, 0);
#pragma unroll
        for (int im = 0; im < 4; im++)
#pragma unroll
            for (int in_ = 0; in_ < 4; in_++)
                acc[im][in_] = __builtin_amdgcn_mfma_f32_16x16x32_f16(af[im], bl[in_], acc[im][in_], 0, 0, 0);
#pragma unroll
        for (int im = 0; im < 4; im++)
#pragma unroll
            for (int in_ = 0; in_ < 4; in_++)
                acc[im][in_] = __builtin_amdgcn_mfma_f32_16x16x32_f16(alo[im], bh[in_], acc[im][in_], 0, 0, 0);
        if (r + 1 < FB_NR) {
            f16x8 h = hi8(a0, a1);
            f16x8 l = lo8(a0, a1, h);
            *(f16x8*)&Alds[cur ^ 1][arow * FB_PITCH + akh]      = h;
            *(f16x8*)&Alds[cur ^ 1][arow * FB_PITCH + 32 + akh] = l;
        }
        __syncthreads();
    }

#pragma unroll
    for (int im = 0; im < 4; im++) {
#pragma unroll
        for (int in_ = 0; in_ < 4; in_++) {
            const int n = wc * 64 + in_ * 16 + fm;
#pragma unroll
            for (int rr = 0; rr < 4; rr++) {
                const int m = bm + wm + im * 16 + quad * 4 + rr;
                unsafeAtomicAdd(&logits[(size_t)m * NEXP + n], acc[im][in_][rr] * 0.00390625f);
            }
        }
    }
}

// ---------------------------------------------------------------------------
// Kernel 2: one wave per token. lane l holds experts 4l..4l+3.
// Replicates jax.lax.top_k semantics exactly. (Unchanged.)
// ---------------------------------------------------------------------------
__global__ __launch_bounds__(256)
void router_topk_kernel(const float* __restrict__ logits,
                        const float* __restrict__ bias,
                        const float* __restrict__ corr,
                        float* __restrict__ out)
{
    const int lane = threadIdx.x & 63;
    const int wave = threadIdx.x >> 6;
    const int t = blockIdx.x * 4 + wave;
    const float* row = logits + (size_t)t * NEXP;
    const int e0 = lane << 2;

    float4 lg = *(const float4*)(row + e0);
    float4 bb = *(const float4*)(bias + e0);
    float4 cc = *(const float4*)(corr + e0);

    float xs[4] = {lg.x + bb.x, lg.y + bb.y, lg.z + bb.z, lg.w + bb.w};
    float cs[4] = {cc.x, cc.y, cc.z, cc.w};
    float s[4], sc[4], mv[4];
#pragma unroll
    for (int i = 0; i < 4; i++) {
        s[i] = 1.0f / (1.0f + expf(-xs[i]));
        sc[i] = s[i] + cs[i];
    }

    float m1 = fmaxf(sc[0], sc[1]);
    float m2 = fminf(sc[0], sc[1]);
    if (sc[2] > m1) { m2 = m1; m1 = sc[2]; } else { m2 = fmaxf(m2, sc[2]); }
    if (sc[3] > m1) { m2 = m1; m1 = sc[3]; } else { m2 = fmaxf(m2, sc[3]); }
#pragma unroll
    for (int off = 1; off <= 4; off <<= 1) {
        float o1 = __shfl_xor(m1, off);
        float o2 = __shfl_xor(m2, off);
        float hi = fmaxf(m1, o1);
        float lo = fminf(m1, o1);
        m1 = hi;
        m2 = fmaxf(lo, fmaxf(m2, o2));
    }
    const float gscore = m1 + m2;

    float gs[8];
#pragma unroll
    for (int j = 0; j < 8; j++) gs[j] = __shfl(gscore, j << 3);
    const int g = lane >> 3;
    int rank = 0;
#pragma unroll
    for (int j = 0; j < 8; j++)
        rank += ((gs[j] > gs[g]) || ((gs[j] == gs[g]) && (j < g))) ? 1 : 0;
    const bool sel = (rank < 4);

#pragma unroll
    for (int i = 0; i < 4; i++) mv[i] = sel ? sc[i] : 0.0f;

    int oidx[8];
    float ow[8];
    float wsum = 0.0f;
#pragma unroll
    for (int r = 0; r < 8; r++) {
        float bv = mv[0]; int bi = e0;
        if (mv[1] > bv) { bv = mv[1]; bi = e0 + 1; }
        if (mv[2] > bv) { bv = mv[2]; bi = e0 + 2; }
        if (mv[3] > bv) { bv = mv[3]; bi = e0 + 3; }
#pragma unroll
        for (int off = 32; off >= 1; off >>= 1) {
            float ov = __shfl_xor(bv, off);
            int oi = __shfl_xor(bi, off);
            if ((ov > bv) || ((ov == bv) && (oi < bi))) { bv = ov; bi = oi; }
        }
        const int wl = bi >> 2;
        const int slot = bi & 3;
        float sraw = (slot == 0) ? s[0] : (slot == 1) ? s[1] : (slot == 2) ? s[2] : s[3];
        sraw = __shfl(sraw, wl);
        if (lane == wl) {
            if (slot == 0) mv[0] = -1e30f;
            else if (slot == 1) mv[1] = -1e30f;
            else if (slot == 2) mv[2] = -1e30f;
            else mv[3] = -1e30f;
        }
        oidx[r] = bi;
        ow[r] = sraw;
        wsum += sraw;
    }

    if (lane == 0) {
        const float d = wsum + 1e-20f;
        float* oi_p = out + (size_t)t * 8;
        float* ow_p = out + (size_t)NTOK * 8 + (size_t)t * 8;
#pragma unroll
        for (int r = 0; r < 8; r++) {
            oi_p[r] = (float)oidx[r];
            ow_p[r] = (ow[r] / d) * 2.5f;
        }
    }
}

extern "C" void kernel_launch(void* const* d_in, const int* in_sizes, int n_in,
                              void* d_out, int out_size, void* d_ws, size_t ws_size,
                              hipStream_t stream)
{
    const float* hs   = (const float*)d_in[0];   // [8192, 7168]
    const float* W    = (const float*)d_in[1];   // [256, 7168]
    const float* b    = (const float*)d_in[2];   // [256]
    const float* corr = (const float*)d_in[3];   // [256]
    float* out = (float*)d_out;                  // 65536 idx-as-float + 65536 weights
    float* logits = (float*)d_ws;                // 8 MB fp32 accumulator

    // zero the logits accumulator (split-K atomics land here)
    hipMemsetAsync(logits, 0, (size_t)LOGITS_F32 * sizeof(float), stream);

    if (ws_size >= (size_t)WS_NEEDED) {
        _Float16* whi = (_Float16*)((char*)d_ws + (size_t)LOGITS_F32 * 4);
        _Float16* wlo = whi + (size_t)W16_PLANE_F16;
        conv_w_kernel<<<896, 256, 0, stream>>>(W, whi, wlo);
        dim3 g1(KS, NTOK / BM);                  // (8, 32) -> 256 blocks, 1/CU
        router_gemm_v6<<<g1, 512, 0, stream>>>(hs, whi, wlo, logits);
    } else {
        dim3 g1(FB_KS, NTOK / FB_BM);
        router_gemm_fb<<<g1, 512, 0, stream>>>(hs, W, logits);
    }
    router_topk_kernel<<<NTOK / 4, 256, 0, stream>>>(logits, b, corr, out);
}

// Round 6
// 408.924 us; speedup vs baseline: 1.3560x; 1.0268x over previous
//
#include <hip/hip_runtime.h>
#include <math.h>

#define HDIM 7168
#define NEXP 256
#define NTOK 8192

// ---- v7 geometry ----
#define KS 8                  // k-splits (== XCD count)
#define KSTEPS 224            // HDIM/32 global k-steps
#define KCH (HDIM / KS)       // 896 source-k per block
#define NR (KCH / 32)         // 28 k-steps per block
#define BM 128                // block m rows
#define NTILES 16             // NEXP/16 n-tiles

#define LOGITS_F32 (NTOK * NEXP)                  // 8 MB fp32
#define W16_PLANE_F16 (NTILES * KSTEPS * 512)     // 1,835,008 f16 = 3.5 MB
#define WS_NEEDED (LOGITS_F32 * 4 + 2 * W16_PLANE_F16 * 2)   // 15,728,640 B

typedef _Float16 f16x8 __attribute__((ext_vector_type(8)));
typedef float f32x4 __attribute__((ext_vector_type(4)));

__device__ __forceinline__ f16x8 hi8(float4 u, float4 v) {
    f16x8 h;
    h[0] = (_Float16)u.x; h[1] = (_Float16)u.y; h[2] = (_Float16)u.z; h[3] = (_Float16)u.w;
    h[4] = (_Float16)v.x; h[5] = (_Float16)v.y; h[6] = (_Float16)v.z; h[7] = (_Float16)v.w;
    return h;
}
__device__ __forceinline__ f16x8 lo8(float4 u, float4 v, f16x8 h) {
    f16x8 l;
    l[0] = (_Float16)(u.x - (float)h[0]); l[1] = (_Float16)(u.y - (float)h[1]);
    l[2] = (_Float16)(u.z - (float)h[2]); l[3] = (_Float16)(u.w - (float)h[3]);
    l[4] = (_Float16)(v.x - (float)h[4]); l[5] = (_Float16)(v.y - (float)h[5]);
    l[6] = (_Float16)(v.z - (float)h[6]); l[7] = (_Float16)(v.w - (float)h[7]);
    return l;
}

// async global->LDS, 16B per lane: LDS dest = wave-uniform base + lane*16.
__device__ __forceinline__ void glds16(const _Float16* g, _Float16* l) {
    __builtin_amdgcn_global_load_lds(
        (const __attribute__((address_space(1))) unsigned int*)g,
        (__attribute__((address_space(3))) unsigned int*)l,
        16, 0, 0);
}

// ---------------------------------------------------------------------------
// Kernel 0: W (256x7168 fp32) -> f16 hi/lo planes in MFMA-fragment order.
// Frag f = nt*KSTEPS + ksi: [lane][j] = W[nt*16+(lane&15)][ksi*32+(lane>>4)*8+j]*256.
// (unchanged, proven)
// ---------------------------------------------------------------------------
__global__ __launch_bounds__(256)
void conv_w_kernel(const float* __restrict__ W,
                   _Float16* __restrict__ whi,
                   _Float16* __restrict__ wlo)
{
    const int t = blockIdx.x * 256 + threadIdx.x;
    const int lane = t & 63;
    const int f = t >> 6;
    const int ksi = f % KSTEPS;
    const int nt  = f / KSTEPS;
    const int n = nt * 16 + (lane & 15);
    const int k = ksi * 32 + (lane >> 4) * 8;
    const float* src = W + (size_t)n * HDIM + k;
    float4 u = *(const float4*)(src + 0);
    float4 v = *(const float4*)(src + 4);
    u.x *= 256.0f; u.y *= 256.0f; u.z *= 256.0f; u.w *= 256.0f;
    v.x *= 256.0f; v.y *= 256.0f; v.z *= 256.0f; v.w *= 256.0f;
    f16x8 h = hi8(u, v);
    f16x8 l = lo8(u, v, h);
    *(f16x8*)&whi[(size_t)f * 512 + lane * 8] = h;
    *(f16x8*)&wlo[(size_t)f * 512 + lane * 8] = l;
}

// ---------------------------------------------------------------------------
// Kernel 1 (v7): m97-replica 2-barrier GEMM sized for 2 blocks/CU.
// logits = hs @ W^T, 3-product f16 split (Ah*Bh + Ah*Bl + Al*Bh), W x256.
//
// v6 post-mortem: its vmcnt(12) was a no-op (queue only 12 deep at the wait)
// and the A(r)-convert then forced vmcnt(4), draining the whole load stream
// every step -- same serialization as v5's barrier drain. m97 (874 TF, 37%
// MfmaUtil, the proven plain-HIP reference) hides its per-step drain via
// CO-RESIDENT INDEPENDENT BLOCKS, not via counted vmcnt. v7 reproduces that:
//   * LDS = 32 KB only (single-buffered B planes via global_load_lds)
//     -> 2 independent blocks/CU; one computes while the other drains.
//   * A never touches LDS: per-lane fragment loads (16 rows x 128 B lines,
//     fully coalesced), hi/lo converted in-reg, 1-step reg prefetch.
//     Fits: acc 128 + A 32 + frags 32 + addr ~25 ~= 220 VGPR (2 waves/SIMD).
//   * Correct ledger per step r:
//       s_barrier                       (all waves done reading B(r-1))
//       issue glds B(r) x8              (outstanding: A(r) 8 + glds 8)
//       convert A(r)                    (compiler emits vmcnt(8): drains
//                                        exactly A(r), 1 step of cover)
//       issue A(r+1) x8                 (outstanding: glds 8 + A 8)
//       s_waitcnt vmcnt(8) [tail: 0]    (drains exactly glds B(r); A(r+1)
//                                        STAYS IN FLIGHT across barrier)
//       s_barrier; sched_barrier(0)
//       96 MFMA (B from LDS, A from regs)
// Block 256 thr / 4 waves (2m x 2n-half), tile 128m x 256n, BK=32, KS=8.
// Grid (8, 64) = 512 blocks = exactly 2/CU; blockIdx.x = k-slice = XCD id
// (896 KB W-slice L2-resident). Split-K combined via atomics (/256 epilogue).
// ---------------------------------------------------------------------------
__global__ __launch_bounds__(256, 2)
void router_gemm_v7(const float* __restrict__ hs,
                    const _Float16* __restrict__ whi,
                    const _Float16* __restrict__ wlo,
                    float* __restrict__ logits)
{
    __shared__ __align__(16) _Float16 Blds[32 * 512];   // 32 KB single buffer

    const int tid  = threadIdx.x;
    const int lane = tid & 63;
    const int wave = tid >> 6;            // 0..3
    const int ksb  = blockIdx.x;          // 0..7 (== XCD id)
    const int bm   = blockIdx.y * BM;
    const int ks0  = ksb * NR;            // first global k-step
    const int kb   = ksb * KCH;

    const int wm  = (wave >> 1) << 6;     // m band: 0 / 64
    const int wn2 = wave & 1;             // n half: 0 / 1 (128 cols each)
    const int fm  = lane & 15;
    const int quad = lane >> 4;
    const int F0 = wave * 8;              // this wave's staged frag ids (8)

    // A fragment sources: lane holds A[bm+wm+im*16+fm][k: kb + quad*8 ..+7]
    const float* ap[4];
#pragma unroll
    for (int im = 0; im < 4; im++)
        ap[im] = hs + (size_t)(bm + wm + im * 16 + fm) * HDIM + kb + quad * 8;

    f32x4 acc[4][8];
#pragma unroll
    for (int i = 0; i < 4; i++)
#pragma unroll
        for (int j = 0; j < 8; j++) acc[i][j] = (f32x4)0.0f;

    // ---- prologue: issue A(0) ----
    float4 a0[4], a1[4];
#pragma unroll
    for (int im = 0; im < 4; im++) {
        a0[im] = *(const float4*)(ap[im] + 0);
        a1[im] = *(const float4*)(ap[im] + 4);
    }

#pragma unroll 1
    for (int r = 0; r < NR; ++r) {
        asm volatile("s_barrier" ::: "memory");   // readers of B(r-1) done

        // ---- stage B(r): 8 frags per wave into the single buffer ----
#pragma unroll
        for (int f = 0; f < 8; f++) {
            const int F = F0 + f;
            const int nt = F >> 1;
            const _Float16* plane = (F & 1) ? wlo : whi;
            glds16(plane + ((size_t)nt * KSTEPS + ks0 + r) * 512 + lane * 8,
                   &Blds[F * 512]);
        }

        // ---- convert A(r) (compiler waits vmcnt(8): drains exactly A(r)) ----
        f16x8 af[4], al_[4];
#pragma unroll
        for (int im = 0; im < 4; im++) {
            af[im]  = hi8(a0[im], a1[im]);
            al_[im] = lo8(a0[im], a1[im], af[im]);
        }

        // ---- issue A(r+1) into the now-free regs ----
        if (r + 1 < NR) {
#pragma unroll
            for (int im = 0; im < 4; im++) {
                const float* p = ap[im] + (size_t)(r + 1) * 32;
                a0[im] = *(const float4*)(p + 0);
                a1[im] = *(const float4*)(p + 4);
            }
            asm volatile("s_waitcnt vmcnt(8)" ::: "memory");  // drain glds B(r)
        } else {
            asm volatile("s_waitcnt vmcnt(0)" ::: "memory");  // tail: drain all
        }
        asm volatile("s_barrier" ::: "memory");   // B(r) visible to all waves
        __builtin_amdgcn_sched_barrier(0);

        // ---- 96 MFMA over this 32-k step (8 ntiles x 4 mtiles x 3 prod) ----
#pragma unroll
        for (int j = 0; j < 8; j++) {
            const int ntl = ((wn2 * 8 + j) << 1);
            f16x8 bh = *(const f16x8*)&Blds[(ntl + 0) * 512 + lane * 8];
            f16x8 bl = *(const f16x8*)&Blds[(ntl + 1) * 512 + lane * 8];
#pragma unroll
            for (int im = 0; im < 4; im++)
                acc[im][j] = __builtin_amdgcn_mfma_f32_16x16x32_f16(af[im], bh, acc[im][j], 0, 0, 0);
#pragma unroll
            for (int im = 0; im < 4; im++)
                acc[im][j] = __builtin_amdgcn_mfma_f32_16x16x32_f16(af[im], bl, acc[im][j], 0, 0, 0);
#pragma unroll
            for (int im = 0; im < 4; im++)
                acc[im][j] = __builtin_amdgcn_mfma_f32_16x16x32_f16(al_[im], bh, acc[im][j], 0, 0, 0);
        }
    }

    // ---- epilogue: undo x256 on B, combine K-splits via atomics ----
#pragma unroll
    for (int im = 0; im < 4; im++) {
#pragma unroll
        for (int j = 0; j < 8; j++) {
            const int n = wn2 * 128 + j * 16 + fm;
#pragma unroll
            for (int rr = 0; rr < 4; rr++) {
                const int m = bm + wm + im * 16 + quad * 4 + rr;
                unsafeAtomicAdd(&logits[(size_t)m * NEXP + n], acc[im][j][rr] * 0.00390625f);
            }
        }
    }
}

// ---------------------------------------------------------------------------
// Fallback GEMM (v2, proven absmax=0) used when ws_size < WS_NEEDED.
// ---------------------------------------------------------------------------
#define FB_BM 128
#define FB_KS 4
#define FB_KCH (HDIM / FB_KS)
#define FB_NR (FB_KCH / 32)
#define FB_PITCH 72

__global__ __launch_bounds__(512, 2)
void router_gemm_fb(const float* __restrict__ hs,
                    const float* __restrict__ W,
                    float* __restrict__ logits)
{
    __shared__ __align__(16) _Float16 Alds[2][FB_BM * FB_PITCH];

    const int tid  = threadIdx.x;
    const int lane = tid & 63;
    const int wave = tid >> 6;
    const int kb = blockIdx.x * FB_KCH;
    const int bm = blockIdx.y * FB_BM;

    const int wm = (wave >> 2) << 6;
    const int wc = wave & 3;
    const int fm = lane & 15;
    const int quad = lane >> 4;

    const int arow = tid >> 2;
    const int akh  = (tid & 3) << 3;
    const float* Ap = hs + (size_t)(bm + arow) * HDIM + kb + akh;
    const float* Bp = W + (size_t)(wc * 64 + fm) * HDIM + kb + quad * 8;

    f32x4 acc[4][4];
#pragma unroll
    for (int i = 0; i < 4; i++)
#pragma unroll
        for (int j = 0; j < 4; j++) acc[i][j] = (f32x4)0.0f;

    float4 a0 = *(const float4*)(Ap + 0);
    float4 a1 = *(const float4*)(Ap + 4);
    float4 bu[4], bv[4];
#pragma unroll
    for (int i = 0; i < 4; i++) {
        const float* q = Bp + (size_t)i * (16 * HDIM);
        bu[i] = *(const float4*)(q + 0);
        bv[i] = *(const float4*)(q + 4);
    }
    {
        f16x8 h = hi8(a0, a1);
        f16x8 l = lo8(a0, a1, h);
        *(f16x8*)&Alds[0][arow * FB_PITCH + akh]      = h;
        *(f16x8*)&Alds[0][arow * FB_PITCH + 32 + akh] = l;
    }
    __syncthreads();

#pragma unroll 2
    for (int r = 0; r < FB_NR; ++r) {
        const int cur = r & 1;
        f16x8 bh[4], bl[4];
#pragma unroll
        for (int i = 0; i < 4; i++) {
            float4 s0 = make_float4(bu[i].x * 256.0f, bu[i].y * 256.0f,
                                    bu[i].z * 256.0f, bu[i].w * 256.0f);
            float4 s1 = make_float4(bv[i].x * 256.0f, bv[i].y * 256.0f,
                                    bv[i].z * 256.0f, bv[i].w * 256.0f);
            bh[i] = hi8(s0, s1);
            bl[i] = lo8(s0, s1, bh[i]);
        }
        if (r + 1 < FB_NR) {
            const float* An = Ap + (r + 1) * 32;
            a0 = *(const float4*)(An + 0);
            a1 = *(const float4*)(An + 4);
            const float* Bn = Bp + (r + 1) * 32;
#pragma unroll
            for (int i = 0; i < 4; i++) {
                const float* q = Bn + (size_t)i * (16 * HDIM);
                bu[i] = *(const float4*)(q + 0);
                bv[i] = *(const float4*)(q + 4);
            }
        }
        f16x8 af[4], alo[4];
#pragma unroll
        for (int im = 0; im < 4; im++) {
            const int off = (wm + im * 16 + fm) * FB_PITCH + quad * 8;
            af[im]  = *(const f16x8*)&Alds[cur][off];
            alo[im] = *(const f16x8*)&Alds[cur][off + 32];
        }
#pragma unroll
        for (int im = 0; im < 4; im++)
#pragma unroll
            for (int in_ = 0; in_ < 4; in_++)
                acc[im][in_] = __builtin_amdgcn_mfma_f32_16x16x32_f16(af[im], bh[in_], acc[im][in_], 0, 0, 0);
#pragma unroll
        for (int im = 0; im < 4; im++)
#pragma unroll
            for (int in_ = 0; in_ < 4; in_++)
                acc[im][in_] = __builtin_amdgcn_mfma_f32_16x16x32_f16(af[im], bl[in_], acc[im][in_], 0, 0, 0);
#pragma unroll
        for (int im = 0; im < 4; im++)
#pragma unroll
            for (int in_ = 0; in_ < 4; in_++)
                acc[im][in_] = __builtin_amdgcn_mfma_f32_16x16x32_f16(alo[im], bh[in_], acc[im][in_], 0, 0, 0);
        if (r + 1 < FB_NR) {
            f16x8 h = hi8(a0, a1);
            f16x8 l = lo8(a0, a1, h);
            *(f16x8*)&Alds[cur ^ 1][arow * FB_PITCH + akh]      = h;
            *(f16x8*)&Alds[cur ^ 1][arow * FB_PITCH + 32 + akh] = l;
        }
        __syncthreads();
    }

#pragma unroll
    for (int im = 0; im < 4; im++) {
#pragma unroll
        for (int in_ = 0; in_ < 4; in_++) {
            const int n = wc * 64 + in_ * 16 + fm;
#pragma unroll
            for (int rr = 0; rr < 4; rr++) {
                const int m = bm + wm + im * 16 + quad * 4 + rr;
                unsafeAtomicAdd(&logits[(size_t)m * NEXP + n], acc[im][in_][rr] * 0.00390625f);
            }
        }
    }
}

// ---------------------------------------------------------------------------
// Kernel 2: one wave per token. lane l holds experts 4l..4l+3.
// Replicates jax.lax.top_k semantics exactly. (Unchanged.)
// ---------------------------------------------------------------------------
__global__ __launch_bounds__(256)
void router_topk_kernel(const float* __restrict__ logits,
                        const float* __restrict__ bias,
                        const float* __restrict__ corr,
                        float* __restrict__ out)
{
    const int lane = threadIdx.x & 63;
    const int wave = threadIdx.x >> 6;
    const int t = blockIdx.x * 4 + wave;
    const float* row = logits + (size_t)t * NEXP;
    const int e0 = lane << 2;

    float4 lg = *(const float4*)(row + e0);
    float4 bb = *(const float4*)(bias + e0);
    float4 cc = *(const float4*)(corr + e0);

    float xs[4] = {lg.x + bb.x, lg.y + bb.y, lg.z + bb.z, lg.w + bb.w};
    float cs[4] = {cc.x, cc.y, cc.z, cc.w};
    float s[4], sc[4], mv[4];
#pragma unroll
    for (int i = 0; i < 4; i++) {
        s[i] = 1.0f / (1.0f + expf(-xs[i]));
        sc[i] = s[i] + cs[i];
    }

    float m1 = fmaxf(sc[0], sc[1]);
    float m2 = fminf(sc[0], sc[1]);
    if (sc[2] > m1) { m2 = m1; m1 = sc[2]; } else { m2 = fmaxf(m2, sc[2]); }
    if (sc[3] > m1) { m2 = m1; m1 = sc[3]; } else { m2 = fmaxf(m2, sc[3]); }
#pragma unroll
    for (int off = 1; off <= 4; off <<= 1) {
        float o1 = __shfl_xor(m1, off);
        float o2 = __shfl_xor(m2, off);
        float hi = fmaxf(m1, o1);
        float lo = fminf(m1, o1);
        m1 = hi;
        m2 = fmaxf(lo, fmaxf(m2, o2));
    }
    const float gscore = m1 + m2;

    float gs[8];
#pragma unroll
    for (int j = 0; j < 8; j++) gs[j] = __shfl(gscore, j << 3);
    const int g = lane >> 3;
    int rank = 0;
#pragma unroll
    for (int j = 0; j < 8; j++)
        rank += ((gs[j] > gs[g]) || ((gs[j] == gs[g]) && (j < g))) ? 1 : 0;
    const bool sel = (rank < 4);

#pragma unroll
    for (int i = 0; i < 4; i++) mv[i] = sel ? sc[i] : 0.0f;

    int oidx[8];
    float ow[8];
    float wsum = 0.0f;
#pragma unroll
    for (int r = 0; r < 8; r++) {
        float bv = mv[0]; int bi = e0;
        if (mv[1] > bv) { bv = mv[1]; bi = e0 + 1; }
        if (mv[2] > bv) { bv = mv[2]; bi = e0 + 2; }
        if (mv[3] > bv) { bv = mv[3]; bi = e0 + 3; }
#pragma unroll
        for (int off = 32; off >= 1; off >>= 1) {
            float ov = __shfl_xor(bv, off);
            int oi = __shfl_xor(bi, off);
            if ((ov > bv) || ((ov == bv) && (oi < bi))) { bv = ov; bi = oi; }
        }
        const int wl = bi >> 2;
        const int slot = bi & 3;
        float sraw = (slot == 0) ? s[0] : (slot == 1) ? s[1] : (slot == 2) ? s[2] : s[3];
        sraw = __shfl(sraw, wl);
        if (lane == wl) {
            if (slot == 0) mv[0] = -1e30f;
            else if (slot == 1) mv[1] = -1e30f;
            else if (slot == 2) mv[2] = -1e30f;
            else mv[3] = -1e30f;
        }
        oidx[r] = bi;
        ow[r] = sraw;
        wsum += sraw;
    }

    if (lane == 0) {
        const float d = wsum + 1e-20f;
        float* oi_p = out + (size_t)t * 8;
        float* ow_p = out + (size_t)NTOK * 8 + (size_t)t * 8;
#pragma unroll
        for (int r = 0; r < 8; r++) {
            oi_p[r] = (float)oidx[r];
            ow_p[r] = (ow[r] / d) * 2.5f;
        }
    }
}

extern "C" void kernel_launch(void* const* d_in, const int* in_sizes, int n_in,
                              void* d_out, int out_size, void* d_ws, size_t ws_size,
                              hipStream_t stream)
{
    const float* hs   = (const float*)d_in[0];   // [8192, 7168]
    const float* W    = (const float*)d_in[1];   // [256, 7168]
    const float* b    = (const float*)d_in[2];   // [256]
    const float* corr = (const float*)d_in[3];   // [256]
    float* out = (float*)d_out;                  // 65536 idx-as-float + 65536 weights
    float* logits = (float*)d_ws;                // 8 MB fp32 accumulator

    // zero the logits accumulator (split-K atomics land here)
    hipMemsetAsync(logits, 0, (size_t)LOGITS_F32 * sizeof(float), stream);

    if (ws_size >= (size_t)WS_NEEDED) {
        _Float16* whi = (_Float16*)((char*)d_ws + (size_t)LOGITS_F32 * 4);
        _Float16* wlo = whi + (size_t)W16_PLANE_F16;
        conv_w_kernel<<<896, 256, 0, stream>>>(W, whi, wlo);
        dim3 g1(KS, NTOK / BM);                  // (8, 64) -> 512 blocks, 2/CU
        router_gemm_v7<<<g1, 256, 0, stream>>>(hs, whi, wlo, logits);
    } else {
        dim3 g1(FB_KS, NTOK / FB_BM);
        router_gemm_fb<<<g1, 512, 0, stream>>>(hs, W, logits);
    }
    router_topk_kernel<<<NTOK / 4, 256, 0, stream>>>(logits, b, corr, out);
}